// Round 1
// 1621.716 us; speedup vs baseline: 1.0040x; 1.0040x over previous
//
#include <hip/hip_runtime.h>
#include <cstdint>
#include <cstddef>

typedef unsigned short u16;
typedef __bf16 bf16x8 __attribute__((ext_vector_type(8)));
typedef float f32x4 __attribute__((ext_vector_type(4)));

#define B_ 2
#define S_ 2048
#define D_ 1024
#define H_ 16
#define G_ 4
#define HD_ 64
#define E_ 8
#define F_ 4096
#define T_ 4096

__device__ __forceinline__ u16 f2b(float f) {
  unsigned u = __float_as_uint(f);
  return (u16)((u + 0x7fffu + ((u >> 16) & 1u)) >> 16);
}
__device__ __forceinline__ float b2f(u16 h) {
  return __uint_as_float(((unsigned)h) << 16);
}

__device__ __forceinline__ float gelu_t(float x) {
  float u = 0.7978845608028654f * (x + 0.044715f * x * x * x);
  float t = 1.f - 2.f / (__expf(2.f * u) + 1.f);
  return 0.5f * x * (1.f + t);
}

__device__ __forceinline__ void gload16(const void* g, void* l) {
  __builtin_amdgcn_global_load_lds((__attribute__((address_space(1))) void*)g,
                                   (__attribute__((address_space(3))) void*)l, 16, 0, 0);
}

// ---------------- small utility kernels ----------------

__global__ void k_zero(int* cnt) {
  if (threadIdx.x < E_) cnt[threadIdx.x] = 0;
}

// batched transpose + f32->bf16 (single): dst[z][C][R] = bf16(src[z][R][C])
__global__ __launch_bounds__(256) void k_transpose(const float* __restrict__ src,
                                                   u16* __restrict__ dst, int R, int C) {
  __shared__ u16 tile[32][33];
  int c0 = blockIdx.x * 32, r0 = blockIdx.y * 32;
  size_t zo = (size_t)blockIdx.z * (size_t)R * (size_t)C;
  int tx = threadIdx.x, ty = threadIdx.y;
  #pragma unroll
  for (int i = ty; i < 32; i += 8) {
    int r = r0 + i, cc = c0 + tx;
    float v = (r < R && cc < C) ? src[zo + (size_t)r * C + cc] : 0.f;
    tile[i][tx] = f2b(v);
  }
  __syncthreads();
  #pragma unroll
  for (int i = ty; i < 32; i += 8) {
    int cc = c0 + i, r = r0 + tx;
    if (cc < C && r < R) dst[zo + (size_t)cc * R + r] = tile[tx][i];
  }
}

// transpose + split f32 -> hi/lo bf16: dsth/dstl[C][R] = split(src[R][C])
__global__ __launch_bounds__(256) void k_split_transpose(const float* __restrict__ src,
                                                         u16* __restrict__ dsth,
                                                         u16* __restrict__ dstl,
                                                         int R, int C) {
  __shared__ float tile[32][33];
  int c0 = blockIdx.x * 32, r0 = blockIdx.y * 32;
  int tx = threadIdx.x, ty = threadIdx.y;
  #pragma unroll
  for (int i = ty; i < 32; i += 8) {
    int r = r0 + i, cc = c0 + tx;
    tile[i][tx] = (r < R && cc < C) ? src[(size_t)r * C + cc] : 0.f;
  }
  __syncthreads();
  #pragma unroll
  for (int i = ty; i < 32; i += 8) {
    int cc = c0 + i, r = r0 + tx;
    if (cc < C && r < R) {
      float v = tile[tx][i];
      u16 h = f2b(v);
      dsth[(size_t)cc * R + r] = h;
      dstl[(size_t)cc * R + r] = f2b(v - b2f(h));
    }
  }
}

// concat bq|bk|bv -> bqkv[1536]
__global__ void k_prep_bias(const float* bq, const float* bk, const float* bv, float* bqkv) {
  int i = blockIdx.x * 256 + threadIdx.x;
  if (i < 1024) bqkv[i] = bq[i];
  else if (i < 1280) bqkv[i] = bk[i - 1024];
  else if (i < 1536) bqkv[i] = bv[i - 1280];
}

// LayerNorm over D=1024; optional fp32 out, bf16 out, hi/lo split out
__global__ __launch_bounds__(256) void k_ln(const float* __restrict__ x,
                                            const float* __restrict__ sc,
                                            const float* __restrict__ bi,
                                            float* __restrict__ of,
                                            u16* __restrict__ ob,
                                            u16* __restrict__ oh,
                                            u16* __restrict__ ol) {
  int t = blockIdx.x, tid = threadIdx.x;
  const float* row = x + (size_t)t * D_;
  float4 v = *(const float4*)&row[tid * 4];
  float s = v.x + v.y + v.z + v.w;
  float ss = v.x * v.x + v.y * v.y + v.z * v.z + v.w * v.w;
  #pragma unroll
  for (int off = 32; off > 0; off >>= 1) {
    s += __shfl_xor(s, off);
    ss += __shfl_xor(ss, off);
  }
  __shared__ float red[8];
  if ((tid & 63) == 0) { red[(tid >> 6) * 2] = s; red[(tid >> 6) * 2 + 1] = ss; }
  __syncthreads();
  float S = red[0] + red[2] + red[4] + red[6];
  float SS = red[1] + red[3] + red[5] + red[7];
  float mu = S * (1.f / D_);
  float var = SS * (1.f / D_) - mu * mu;
  float rs = rsqrtf(var + 1e-6f);
  float4 scv = *(const float4*)&sc[tid * 4];
  float4 biv = *(const float4*)&bi[tid * 4];
  float o[4];
  o[0] = (v.x - mu) * rs * scv.x + biv.x;
  o[1] = (v.y - mu) * rs * scv.y + biv.y;
  o[2] = (v.z - mu) * rs * scv.z + biv.z;
  o[3] = (v.w - mu) * rs * scv.w + biv.w;
  size_t base = (size_t)t * D_ + tid * 4;
  if (of) *(float4*)&of[base] = make_float4(o[0], o[1], o[2], o[3]);
  if (ob) {
    ushort4 u;
    u.x = f2b(o[0]); u.y = f2b(o[1]); u.z = f2b(o[2]); u.w = f2b(o[3]);
    *(ushort4*)&ob[base] = u;
  }
  if (oh) {
    ushort4 uh, ulv;
    #pragma unroll
    for (int i = 0; i < 4; ++i) {
      u16 h = f2b(o[i]);
      u16 lo = f2b(o[i] - b2f(h));
      ((u16*)&uh)[i] = h;
      ((u16*)&ulv)[i] = lo;
    }
    *(ushort4*)&oh[base] = uh;
    *(ushort4*)&ol[base] = ulv;
  }
}

// ---------------- split-bf16 MFMA GEMM ----------------
// C[M,N] = (Ah+Al)[M,K] @ (Bh+Bl)[N,K]^T + bias  (3-term MFMA: hh + hl + lh)
// OUTMODE 0: write Ch/Cl (hi/lo bf16).  OUTMODE 1: write Cf = fp32 + res.
template <int OUTMODE>
__global__ __launch_bounds__(256) void k_gemm_split(const u16* __restrict__ Ah,
                                                    const u16* __restrict__ Al,
                                                    const u16* __restrict__ Bh,
                                                    const u16* __restrict__ Bl,
                                                    const float* __restrict__ bias,
                                                    const float* __restrict__ res,
                                                    u16* __restrict__ Ch,
                                                    u16* __restrict__ Cl,
                                                    float* __restrict__ Cf,
                                                    int M, int N, int K) {
  __shared__ __align__(16) u16 Ash[128 * 32], Asl[128 * 32];
  __shared__ __align__(16) u16 Bsh[128 * 32], Bsl[128 * 32];
  int tid = threadIdx.x, w = tid >> 6, l = tid & 63;
  int quad = l >> 4, l15 = l & 15;
  int m0 = blockIdx.x * 128, n0 = blockIdx.y * 128;
  int koff = (l & 3) * 8;
  const u16 *aph[2], *apl[2], *bph[2], *bpl[2];
  #pragma unroll
  for (int c = 0; c < 2; ++c) {
    int chunk = c * 4 + w;
    int row = m0 + chunk * 16 + (l >> 2);
    aph[c] = Ah + (size_t)row * K + koff;
    apl[c] = Al + (size_t)row * K + koff;
    int nrow = n0 + chunk * 16 + (l >> 2);
    bph[c] = Bh + (size_t)nrow * K + koff;
    bpl[c] = Bl + (size_t)nrow * K + koff;
  }
  f32x4 acc[4][4] = {};
  int wm = (w & 1) * 64, wn = (w >> 1) * 64;
  for (int k0 = 0; k0 < K; k0 += 32) {
    __syncthreads();
    #pragma unroll
    for (int c = 0; c < 2; ++c) {
      gload16(aph[c] + k0, &Ash[(c * 4 + w) * 512]);
      gload16(apl[c] + k0, &Asl[(c * 4 + w) * 512]);
      gload16(bph[c] + k0, &Bsh[(c * 4 + w) * 512]);
      gload16(bpl[c] + k0, &Bsl[(c * 4 + w) * 512]);
    }
    __syncthreads();
    bf16x8 ah[4], al_[4], bh[4], bl_[4];
    #pragma unroll
    for (int i = 0; i < 4; ++i) {
      ah[i] = *(const bf16x8*)&Ash[(wm + i * 16 + l15) * 32 + quad * 8];
      al_[i] = *(const bf16x8*)&Asl[(wm + i * 16 + l15) * 32 + quad * 8];
    }
    #pragma unroll
    for (int j = 0; j < 4; ++j) {
      bh[j] = *(const bf16x8*)&Bsh[(wn + j * 16 + l15) * 32 + quad * 8];
      bl_[j] = *(const bf16x8*)&Bsl[(wn + j * 16 + l15) * 32 + quad * 8];
    }
    #pragma unroll
    for (int i = 0; i < 4; ++i)
      #pragma unroll
      for (int j = 0; j < 4; ++j) {
        acc[i][j] = __builtin_amdgcn_mfma_f32_16x16x32_bf16(ah[i], bh[j], acc[i][j], 0, 0, 0);
        acc[i][j] = __builtin_amdgcn_mfma_f32_16x16x32_bf16(ah[i], bl_[j], acc[i][j], 0, 0, 0);
        acc[i][j] = __builtin_amdgcn_mfma_f32_16x16x32_bf16(al_[i], bh[j], acc[i][j], 0, 0, 0);
      }
  }
  #pragma unroll
  for (int i = 0; i < 4; ++i) {
    #pragma unroll
    for (int j = 0; j < 4; ++j) {
      int gn = n0 + wn + j * 16 + l15;
      float bv = bias[gn];
      #pragma unroll
      for (int r = 0; r < 4; ++r) {
        int gm = m0 + wm + i * 16 + quad * 4 + r;
        size_t idx = (size_t)gm * N + gn;
        float v = acc[i][j][r] + bv;
        if (OUTMODE == 0) {
          u16 h = f2b(v);
          Ch[idx] = h;
          Cl[idx] = f2b(v - b2f(h));
        } else {
          Cf[idx] = v + res[idx];
        }
      }
    }
  }
}

// ---------------- MFMA flash attention with session-delta decay ----------------
#define AP 72  // padded u16 row stride for LDS tiles
__global__ __launch_bounds__(256) void k_attn_mfma(const u16* __restrict__ qkv_h,
                                                   const u16* __restrict__ qkv_l,
                                                   const float* __restrict__ sd,
                                                   const float* __restrict__ td,
                                                   u16* __restrict__ o_h,
                                                   u16* __restrict__ o_l) {
  __shared__ __align__(16) u16 Qh[64 * AP], Ql[64 * AP];
  __shared__ __align__(16) u16 Kh[64 * AP], Kl[64 * AP];
  __shared__ __align__(16) u16 Vth[64 * AP], Vtl[64 * AP];
  __shared__ __align__(16) u16 Ph[4][16 * AP], Pl[4][16 * AP];
  __shared__ float sds[64];
  int tid = threadIdx.x, w = tid >> 6, l = tid & 63;
  int quad = l >> 4, l15 = l & 15;
  int q0 = blockIdx.x * 64, h = blockIdx.y, b = blockIdx.z;
  int g = h >> 2;
  int r = tid >> 2, cb = (tid & 3) * 16;

  {
    const u16* gq_h = qkv_h + (size_t)(b * S_ + q0 + r) * 1536 + h * HD_ + cb;
    const u16* gq_l = qkv_l + (size_t)(b * S_ + q0 + r) * 1536 + h * HD_ + cb;
    #pragma unroll
    for (int c = 0; c < 4; ++c) {
      *(ushort4*)&Qh[r * AP + cb + c * 4] = *(const ushort4*)&gq_h[c * 4];
      *(ushort4*)&Ql[r * AP + cb + c * 4] = *(const ushort4*)&gq_l[c * 4];
    }
  }
  __syncthreads();
  bf16x8 aqh[2], aql[2];
  #pragma unroll
  for (int kk = 0; kk < 2; ++kk) {
    aqh[kk] = *(const bf16x8*)&Qh[(w * 16 + l15) * AP + kk * 32 + quad * 8];
    aql[kk] = *(const bf16x8*)&Ql[(w * 16 + l15) * AP + kk * 32 + quad * 8];
  }
  float sp = log1pf(__expf(td[h]));
  float dq[4];
  #pragma unroll
  for (int i = 0; i < 4; ++i) dq[i] = sd[b * S_ + q0 + w * 16 + quad * 4 + i];

  float mr[4], lr[4];
  f32x4 oa[4] = {};
  #pragma unroll
  for (int i = 0; i < 4; ++i) { mr[i] = -3.0e38f; lr[i] = 0.f; }

  for (int s0 = 0; s0 < S_; s0 += 64) {
    const u16* gk_h = qkv_h + (size_t)(b * S_ + s0 + r) * 1536 + 1024 + g * HD_ + cb;
    const u16* gk_l = qkv_l + (size_t)(b * S_ + s0 + r) * 1536 + 1024 + g * HD_ + cb;
    const u16* gv_h = qkv_h + (size_t)(b * S_ + s0 + r) * 1536 + 1280 + g * HD_ + cb;
    const u16* gv_l = qkv_l + (size_t)(b * S_ + s0 + r) * 1536 + 1280 + g * HD_ + cb;
    ushort4 kh4[4], kl4[4];
    u16 vh[16], vl[16];
    #pragma unroll
    for (int c = 0; c < 4; ++c) {
      kh4[c] = *(const ushort4*)&gk_h[c * 4];
      kl4[c] = *(const ushort4*)&gk_l[c * 4];
      *(ushort4*)&vh[c * 4] = *(const ushort4*)&gv_h[c * 4];
      *(ushort4*)&vl[c * 4] = *(const ushort4*)&gv_l[c * 4];
    }
    __syncthreads();
    #pragma unroll
    for (int c = 0; c < 4; ++c) {
      *(ushort4*)&Kh[r * AP + cb + c * 4] = kh4[c];
      *(ushort4*)&Kl[r * AP + cb + c * 4] = kl4[c];
    }
    #pragma unroll
    for (int i = 0; i < 16; ++i) {
      Vth[(cb + i) * AP + r] = vh[i];
      Vtl[(cb + i) * AP + r] = vl[i];
    }
    if (tid < 64) sds[tid] = sd[b * S_ + s0 + tid];
    __syncthreads();

    f32x4 sc[4] = {};
    #pragma unroll
    for (int j = 0; j < 4; ++j) {
      #pragma unroll
      for (int kk = 0; kk < 2; ++kk) {
        bf16x8 bkh = *(const bf16x8*)&Kh[(j * 16 + l15) * AP + kk * 32 + quad * 8];
        bf16x8 bkl = *(const bf16x8*)&Kl[(j * 16 + l15) * AP + kk * 32 + quad * 8];
        sc[j] = __builtin_amdgcn_mfma_f32_16x16x32_bf16(aqh[kk], bkh, sc[j], 0, 0, 0);
        sc[j] = __builtin_amdgcn_mfma_f32_16x16x32_bf16(aqh[kk], bkl, sc[j], 0, 0, 0);
        sc[j] = __builtin_amdgcn_mfma_f32_16x16x32_bf16(aql[kk], bkh, sc[j], 0, 0, 0);
      }
    }
    float ds_[4];
    #pragma unroll
    for (int j = 0; j < 4; ++j) ds_[j] = sds[j * 16 + l15];
    float s_[4][4];
    #pragma unroll
    for (int j = 0; j < 4; ++j)
      #pragma unroll
      for (int i = 0; i < 4; ++i)
        s_[j][i] = sc[j][i] * 0.125f - sp * fabsf(dq[i] - ds_[j]);
    float mx[4];
    #pragma unroll
    for (int i = 0; i < 4; ++i)
      mx[i] = fmaxf(fmaxf(s_[0][i], s_[1][i]), fmaxf(s_[2][i], s_[3][i]));
    #pragma unroll
    for (int d = 1; d < 16; d <<= 1)
      #pragma unroll
      for (int i = 0; i < 4; ++i) mx[i] = fmaxf(mx[i], __shfl_xor(mx[i], d));
    float al[4], rsum[4], p[4][4];
    #pragma unroll
    for (int i = 0; i < 4; ++i) {
      float mn = fmaxf(mr[i], mx[i]);
      al[i] = __expf(mr[i] - mn);
      mr[i] = mn;
      rsum[i] = 0.f;
      #pragma unroll
      for (int j = 0; j < 4; ++j) { p[j][i] = __expf(s_[j][i] - mn); rsum[i] += p[j][i]; }
    }
    #pragma unroll
    for (int d = 1; d < 16; d <<= 1)
      #pragma unroll
      for (int i = 0; i < 4; ++i) rsum[i] += __shfl_xor(rsum[i], d);
    #pragma unroll
    for (int i = 0; i < 4; ++i) {
      lr[i] = lr[i] * al[i] + rsum[i];
      #pragma unroll
      for (int j = 0; j < 4; ++j) oa[j][i] *= al[i];
    }
    #pragma unroll
    for (int j = 0; j < 4; ++j)
      #pragma unroll
      for (int i = 0; i < 4; ++i) {
        float pv = p[j][i];
        u16 hv = f2b(pv);
        Ph[w][(quad * 4 + i) * AP + j * 16 + l15] = hv;
        Pl[w][(quad * 4 + i) * AP + j * 16 + l15] = f2b(pv - b2f(hv));
      }
    bf16x8 aph[2], apl[2];
    #pragma unroll
    for (int kk = 0; kk < 2; ++kk) {
      aph[kk] = *(const bf16x8*)&Ph[w][l15 * AP + kk * 32 + quad * 8];
      apl[kk] = *(const bf16x8*)&Pl[w][l15 * AP + kk * 32 + quad * 8];
    }
    #pragma unroll
    for (int j = 0; j < 4; ++j) {
      #pragma unroll
      for (int kk = 0; kk < 2; ++kk) {
        bf16x8 bvh = *(const bf16x8*)&Vth[(j * 16 + l15) * AP + kk * 32 + quad * 8];
        bf16x8 bvl = *(const bf16x8*)&Vtl[(j * 16 + l15) * AP + kk * 32 + quad * 8];
        oa[j] = __builtin_amdgcn_mfma_f32_16x16x32_bf16(aph[kk], bvh, oa[j], 0, 0, 0);
        oa[j] = __builtin_amdgcn_mfma_f32_16x16x32_bf16(aph[kk], bvl, oa[j], 0, 0, 0);
        oa[j] = __builtin_amdgcn_mfma_f32_16x16x32_bf16(apl[kk], bvh, oa[j], 0, 0, 0);
      }
    }
  }
  #pragma unroll
  for (int i = 0; i < 4; ++i) {
    float inv = 1.f / lr[i];
    int q = b * S_ + q0 + w * 16 + quad * 4 + i;
    #pragma unroll
    for (int j = 0; j < 4; ++j) {
      float ov = oa[j][i] * inv;
      size_t idx = (size_t)q * (H_ * HD_) + h * HD_ + j * 16 + l15;
      u16 hv = f2b(ov);
      o_h[idx] = hv;
      o_l[idx] = f2b(ov - b2f(hv));
    }
  }
}

// ---------------- router ----------------
__global__ __launch_bounds__(256) void k_router(const float* __restrict__ xn2,
                                                const float* __restrict__ rw,
                                                const float* __restrict__ rb,
                                                int* __restrict__ eidx, int* __restrict__ epos,
                                                float* __restrict__ ew, int* __restrict__ cnt,
                                                int* __restrict__ list) {
  int t = blockIdx.x * 4 + (threadIdx.x >> 6);
  int l = threadIdx.x & 63;
  const float* row = xn2 + (size_t)t * D_;
  float acc[8];
  #pragma unroll
  for (int e = 0; e < 8; ++e) acc[e] = 0.f;
  for (int i = 0; i < 16; ++i) {
    int d = l + i * 64;
    float xv = row[d];
    float4 w0 = *(const float4*)&rw[d * 8 + 0];
    float4 w1 = *(const float4*)&rw[d * 8 + 4];
    acc[0] = fmaf(xv, w0.x, acc[0]); acc[1] = fmaf(xv, w0.y, acc[1]);
    acc[2] = fmaf(xv, w0.z, acc[2]); acc[3] = fmaf(xv, w0.w, acc[3]);
    acc[4] = fmaf(xv, w1.x, acc[4]); acc[5] = fmaf(xv, w1.y, acc[5]);
    acc[6] = fmaf(xv, w1.z, acc[6]); acc[7] = fmaf(xv, w1.w, acc[7]);
  }
  #pragma unroll
  for (int off = 32; off > 0; off >>= 1)
    #pragma unroll
    for (int e = 0; e < 8; ++e) acc[e] += __shfl_xor(acc[e], off);
  if (l == 0) {
    float lg[8];
    #pragma unroll
    for (int e = 0; e < 8; ++e) lg[e] = acc[e] + rb[e];
    int i1 = 0;
    #pragma unroll
    for (int e = 1; e < 8; ++e) if (lg[e] > lg[i1]) i1 = e;
    int i2 = (i1 == 0) ? 1 : 0;
    #pragma unroll
    for (int e = 0; e < 8; ++e) if (e != i1 && lg[e] > lg[i2]) i2 = e;
    float wa = 1.f / (1.f + __expf(lg[i2] - lg[i1]));
    float wb = 1.f - wa;
    int pa = atomicAdd(&cnt[i1], 1);
    int pb = atomicAdd(&cnt[i2], 1);
    list[i1 * T_ + pa] = t;
    list[i2 * T_ + pb] = t;
    eidx[2 * t] = i1; eidx[2 * t + 1] = i2;
    epos[2 * t] = pa; epos[2 * t + 1] = pb;
    ew[2 * t] = wa; ew[2 * t + 1] = wb;
  }
}

__global__ void k_offsets(const int* __restrict__ cnt, int* __restrict__ offs) {
  if (threadIdx.x == 0 && blockIdx.x == 0) {
    int tot = 0;
    for (int e = 0; e < E_; ++e) { offs[e] = tot; tot += cnt[e]; }
  }
}

// ---------------- gather A rows densely per expert slot ----------------
// dst[offs[e]+i][:] = src[list[e*T_+i]][:]  — turns the MoE GEMM's random
// row gather into streaming loads inside the latency-critical loop.
__global__ __launch_bounds__(128) void k_gather(const u16* __restrict__ src,
                                                const int* __restrict__ offs,
                                                const int* __restrict__ list,
                                                u16* __restrict__ dst) {
  int s = blockIdx.x;  // slot 0 .. 2*T_-1
  int e = 0;
  #pragma unroll
  for (int i = 1; i < E_; ++i) e = (s >= offs[i]) ? i : e;
  int tok = list[e * T_ + (s - offs[e])];
  int l = threadIdx.x;  // 128 threads x 8 u16 = 1024
  ushort4 a = *(const ushort4*)&src[(size_t)tok * D_ + l * 8];
  ushort4 b = *(const ushort4*)&src[(size_t)tok * D_ + l * 8 + 4];
  *(ushort4*)&dst[(size_t)s * D_ + l * 8] = a;
  *(ushort4*)&dst[(size_t)s * D_ + l * 8 + 4] = b;
}

// ---------------- bf16 MFMA GEMM for MoE ----------------
// 3-buffer LDS, depth-2 prefetch, counted vmcnt (never drained to 0 in the
// main loop), raw s_barrier.  A is dense slot-indexed (pre-gathered for
// MODE 0; MODE 1 reads hb which is produced slot-indexed).
// MODE 0: h[slot] = gelu(A[slot] @ w1t[e]^T + b1[e]) -> u16
// MODE 1: y[slot] = h[slot] @ w2t[e]^T + b2[e]       -> u16
template <int MODE>
__global__ __launch_bounds__(256) void k_moe_gemm(const u16* __restrict__ Ab,
                                                  const u16* __restrict__ Wt,
                                                  const float* __restrict__ bias,
                                                  u16* __restrict__ outU,
                                                  const int* __restrict__ cnt,
                                                  const int* __restrict__ offs,
                                                  int N, int K) {
  int e = blockIdx.z;
  int myM = cnt[e];
  int m0 = blockIdx.x * 128;
  if (m0 >= myM) return;
  int n0 = blockIdx.y * 128;
  __shared__ __align__(16) u16 As[3][128 * 32];
  __shared__ __align__(16) u16 Bs[3][128 * 32];
  int tid = threadIdx.x, w = tid >> 6, l = tid & 63;
  int quad = l >> 4, l15 = l & 15;
  int koff = (l & 3) * 8;
  const u16* ap[2];
  const u16* bp[2];
  #pragma unroll
  for (int c = 0; c < 2; ++c) {
    int chunk = c * 4 + w;
    int r = m0 + chunk * 16 + (l >> 2);
    int rr = (r < myM) ? r : (myM - 1);
    ap[c] = Ab + (size_t)(offs[e] + rr) * K + koff;
    int nrow = n0 + chunk * 16 + (l >> 2);
    bp[c] = Wt + (size_t)e * N * K + (size_t)nrow * K + koff;
  }
  f32x4 acc[4][4] = {};
  int wm = (w & 1) * 64, wn = (w >> 1) * 64;
  int nsteps = K >> 5;  // 32 (MODE 0) or 128 (MODE 1), always >= 2
  // prologue: stage K-tiles 0 and 1 into buffers 0 and 1
  #pragma unroll
  for (int c = 0; c < 2; ++c) {
    gload16(ap[c], &As[0][(c * 4 + w) * 512]);
    gload16(bp[c], &Bs[0][(c * 4 + w) * 512]);
  }
  #pragma unroll
  for (int c = 0; c < 2; ++c) {
    gload16(ap[c] + 32, &As[1][(c * 4 + w) * 512]);
    gload16(bp[c] + 32, &Bs[1][(c * 4 + w) * 512]);
  }
  int cur = 0, stg = 2;
  for (int it = 0; it < nsteps - 1; ++it) {
    // wait until stage(it) has landed; stage(it+1) (4 loads) stays in flight
    asm volatile("s_waitcnt vmcnt(4)" ::: "memory");
    asm volatile("s_barrier" ::: "memory");
    if (it < nsteps - 2) {
      int k0 = (it + 2) << 5;
      #pragma unroll
      for (int c = 0; c < 2; ++c) {
        gload16(ap[c] + k0, &As[stg][(c * 4 + w) * 512]);
        gload16(bp[c] + k0, &Bs[stg][(c * 4 + w) * 512]);
      }
    }
    bf16x8 af[4], bfv[4];
    #pragma unroll
    for (int i = 0; i < 4; ++i)
      af[i] = *(const bf16x8*)&As[cur][(wm + i * 16 + l15) * 32 + quad * 8];
    #pragma unroll
    for (int j = 0; j < 4; ++j)
      bfv[j] = *(const bf16x8*)&Bs[cur][(wn + j * 16 + l15) * 32 + quad * 8];
    __builtin_amdgcn_s_setprio(1);
    #pragma unroll
    for (int i = 0; i < 4; ++i)
      #pragma unroll
      for (int j = 0; j < 4; ++j)
        acc[i][j] = __builtin_amdgcn_mfma_f32_16x16x32_bf16(af[i], bfv[j], acc[i][j], 0, 0, 0);
    __builtin_amdgcn_s_setprio(0);
    cur = (cur == 2) ? 0 : cur + 1;
    stg = (stg == 2) ? 0 : stg + 1;
  }
  // tail iteration: only the last stage is outstanding — drain it
  asm volatile("s_waitcnt vmcnt(0)" ::: "memory");
  asm volatile("s_barrier" ::: "memory");
  {
    bf16x8 af[4], bfv[4];
    #pragma unroll
    for (int i = 0; i < 4; ++i)
      af[i] = *(const bf16x8*)&As[cur][(wm + i * 16 + l15) * 32 + quad * 8];
    #pragma unroll
    for (int j = 0; j < 4; ++j)
      bfv[j] = *(const bf16x8*)&Bs[cur][(wn + j * 16 + l15) * 32 + quad * 8];
    __builtin_amdgcn_s_setprio(1);
    #pragma unroll
    for (int i = 0; i < 4; ++i)
      #pragma unroll
      for (int j = 0; j < 4; ++j)
        acc[i][j] = __builtin_amdgcn_mfma_f32_16x16x32_bf16(af[i], bfv[j], acc[i][j], 0, 0, 0);
    __builtin_amdgcn_s_setprio(0);
  }
  const float* bptr = bias + (size_t)e * N;
  #pragma unroll
  for (int i = 0; i < 4; ++i) {
    #pragma unroll
    for (int j = 0; j < 4; ++j) {
      int gn = n0 + wn + j * 16 + l15;
      float bv = bptr[gn];
      #pragma unroll
      for (int r = 0; r < 4; ++r) {
        int gm = m0 + wm + i * 16 + quad * 4 + r;
        if (gm < myM) {
          float vv = acc[i][j][r] + bv;
          if (MODE == 0) vv = gelu_t(vv);
          outU[(size_t)(offs[e] + gm) * N + gn] = f2b(vv);
        }
      }
    }
  }
}

// ---------------- final combine ----------------
__global__ __launch_bounds__(256) void k_combine(const float* __restrict__ x1,
                                                 const u16* __restrict__ y,
                                                 const int* __restrict__ eidx,
                                                 const int* __restrict__ epos,
                                                 const float* __restrict__ ew,
                                                 const int* __restrict__ offs,
                                                 float* __restrict__ out) {
  int t = blockIdx.x, tid = threadIdx.x;
  int e0 = eidx[2 * t], e1 = eidx[2 * t + 1];
  int s0 = offs[e0] + epos[2 * t];
  int s1 = offs[e1] + epos[2 * t + 1];
  float w0 = ew[2 * t], w1 = ew[2 * t + 1];
  int d = tid * 4;
  float4 a = *(const float4*)&x1[(size_t)t * D_ + d];
  ushort4 y0 = *(const ushort4*)&y[(size_t)s0 * D_ + d];
  ushort4 y1 = *(const ushort4*)&y[(size_t)s1 * D_ + d];
  float4 r;
  r.x = a.x + w0 * b2f(y0.x) + w1 * b2f(y1.x);
  r.y = a.y + w0 * b2f(y0.y) + w1 * b2f(y1.y);
  r.z = a.z + w0 * b2f(y0.z) + w1 * b2f(y1.z);
  r.w = a.w + w0 * b2f(y0.w) + w1 * b2f(y1.w);
  *(float4*)&out[(size_t)t * D_ + d] = r;
}

// ---------------- launch ----------------
extern "C" void kernel_launch(void* const* d_in, const int* in_sizes, int n_in,
                              void* d_out, int out_size, void* d_ws, size_t ws_size,
                              hipStream_t stream) {
  (void)in_sizes; (void)n_in; (void)out_size; (void)ws_size;
  const float* x    = (const float*)d_in[0];
  const float* sd   = (const float*)d_in[1];
  const float* ln1s = (const float*)d_in[2];
  const float* ln1b = (const float*)d_in[3];
  const float* wq   = (const float*)d_in[4];
  const float* bq   = (const float*)d_in[5];
  const float* wk   = (const float*)d_in[6];
  const float* bk   = (const float*)d_in[7];
  const float* wv   = (const float*)d_in[8];
  const float* bv   = (const float*)d_in[9];
  const float* wo   = (const float*)d_in[10];
  const float* bo   = (const float*)d_in[11];
  const float* td   = (const float*)d_in[12];
  const float* ln2s = (const float*)d_in[13];
  const float* ln2b = (const float*)d_in[14];
  const float* rw   = (const float*)d_in[15];
  const float* rb   = (const float*)d_in[16];
  const float* w1   = (const float*)d_in[17];
  const float* b1   = (const float*)d_in[18];
  const float* w2   = (const float*)d_in[19];
  const float* b2   = (const float*)d_in[20];
  float* out = (float*)d_out;

  const size_t MBy = 1024ull * 1024ull;
  char* ws = (char*)d_ws;
  u16*   w1t   = (u16*)(ws + 0);          // 64MB   [prep -> moe1]
  u16*   w2t   = (u16*)(ws + 64 * MBy);   // 64MB   [prep -> moe2]
  u16*   hb    = (u16*)(ws + 128 * MBy);  // 64MB   [moe1 -> moe2]
  float* xn2   = (float*)(ws + 128 * MBy);// 16MB   aliases hb (dead before moe1)
  u16*   wqkvTh= (u16*)(ws + 192 * MBy);  // 3MB
  u16*   wqkvTl= (u16*)(ws + 195 * MBy);  // 3MB
  u16*   woTh  = (u16*)(ws + 198 * MBy);  // 2MB
  u16*   woTl  = (u16*)(ws + 200 * MBy);  // 2MB
  float* bqkv  = (float*)(ws + 202 * MBy);// 6KB
  int*   eidx  = (int*)(ws + 202 * MBy + 65536);
  int*   epos  = eidx + 2 * T_;
  float* ew    = (float*)(epos + 2 * T_);
  int*   list  = (int*)(ew + 2 * T_);
  int*   cnt   = list + E_ * T_;
  int*   offs  = cnt + E_;
  u16*   xn_h  = (u16*)(ws + 203 * MBy);  // 8MB    [ln1 -> qkv gemm]
  u16*   xn_l  = (u16*)(ws + 211 * MBy);  // 8MB
  u16*   xn2b  = (u16*)(ws + 203 * MBy);  // 8MB    aliases xn_h (dead)
  u16*   qkv_h = (u16*)(ws + 219 * MBy);  // 13MB   [qkv -> attn]
  u16*   qkv_l = (u16*)(ws + 232 * MBy);  // 13MB
  u16*   yb    = (u16*)(ws + 219 * MBy);  // 16MB   aliases qkv (dead after attn)
  u16*   o_h   = (u16*)(ws + 245 * MBy);  // 8MB    [attn -> outproj]
  u16*   o_l   = (u16*)(ws + 253 * MBy);  // 8MB
  u16*   aprime= (u16*)(ws + 245 * MBy);  // 16MB   aliases o_h/o_l (dead after outproj)
  float* x1    = (float*)(ws + 261 * MBy);// 16MB   [outproj -> combine]

  k_zero<<<1, 64, 0, stream>>>(cnt);
  k_transpose<<<dim3(F_ / 32, D_ / 32, E_), dim3(32, 8), 0, stream>>>(w1, w1t, D_, F_);
  k_transpose<<<dim3(D_ / 32, F_ / 32, E_), dim3(32, 8), 0, stream>>>(w2, w2t, F_, D_);
  k_split_transpose<<<dim3(1024 / 32, 1024 / 32), dim3(32, 8), 0, stream>>>(wq, wqkvTh, wqkvTl, 1024, 1024);
  k_split_transpose<<<dim3(256 / 32, 1024 / 32), dim3(32, 8), 0, stream>>>(wk, wqkvTh + 1024 * 1024, wqkvTl + 1024 * 1024, 1024, 256);
  k_split_transpose<<<dim3(256 / 32, 1024 / 32), dim3(32, 8), 0, stream>>>(wv, wqkvTh + 1280 * 1024, wqkvTl + 1280 * 1024, 1024, 256);
  k_split_transpose<<<dim3(1024 / 32, 1024 / 32), dim3(32, 8), 0, stream>>>(wo, woTh, woTl, 1024, 1024);
  k_prep_bias<<<6, 256, 0, stream>>>(bq, bk, bv, bqkv);

  k_ln<<<T_, 256, 0, stream>>>(x, ln1s, ln1b, nullptr, nullptr, xn_h, xn_l);

  k_gemm_split<0><<<dim3(T_ / 128, 1536 / 128), 256, 0, stream>>>(
      xn_h, xn_l, wqkvTh, wqkvTl, bqkv, nullptr, qkv_h, qkv_l, nullptr, T_, 1536, 1024);

  k_attn_mfma<<<dim3(S_ / 64, H_, B_), 256, 0, stream>>>(qkv_h, qkv_l, sd, td, o_h, o_l);

  k_gemm_split<1><<<dim3(T_ / 128, 1024 / 128), 256, 0, stream>>>(
      o_h, o_l, woTh, woTl, bo, x, nullptr, nullptr, x1, T_, 1024, 1024);

  k_ln<<<T_, 256, 0, stream>>>(x1, ln2s, ln2b, xn2, xn2b, nullptr, nullptr);

  k_router<<<T_ / 4, 256, 0, stream>>>(xn2, rw, rb, eidx, epos, ew, cnt, list);
  k_offsets<<<1, 64, 0, stream>>>(cnt, offs);
  k_gather<<<2 * T_, 128, 0, stream>>>(xn2b, offs, list, aprime);

  k_moe_gemm<0><<<dim3(32, F_ / 128, E_), 256, 0, stream>>>(aprime, w1t, b1, hb, cnt, offs, F_, D_);
  k_moe_gemm<1><<<dim3(32, D_ / 128, E_), 256, 0, stream>>>(hb, w2t, b2, yb, cnt, offs, D_, F_);

  k_combine<<<T_, 256, 0, stream>>>(x1, yb, eidx, epos, ew, offs, out);
}

// Round 2
// 1100.961 us; speedup vs baseline: 1.4788x; 1.4730x over previous
//
#include <hip/hip_runtime.h>
#include <cstdint>
#include <cstddef>

typedef unsigned short u16;
typedef __bf16 bf16x8 __attribute__((ext_vector_type(8)));
typedef float f32x4 __attribute__((ext_vector_type(4)));

#define B_ 2
#define S_ 2048
#define D_ 1024
#define H_ 16
#define G_ 4
#define HD_ 64
#define E_ 8
#define F_ 4096
#define T_ 4096

__device__ __forceinline__ u16 f2b(float f) {
  unsigned u = __float_as_uint(f);
  return (u16)((u + 0x7fffu + ((u >> 16) & 1u)) >> 16);
}
__device__ __forceinline__ float b2f(u16 h) {
  return __uint_as_float(((unsigned)h) << 16);
}

__device__ __forceinline__ float gelu_t(float x) {
  float u = 0.7978845608028654f * (x + 0.044715f * x * x * x);
  float t = 1.f - 2.f / (__expf(2.f * u) + 1.f);
  return 0.5f * x * (1.f + t);
}

__device__ __forceinline__ void gload16(const void* g, void* l) {
  __builtin_amdgcn_global_load_lds((__attribute__((address_space(1))) void*)g,
                                   (__attribute__((address_space(3))) void*)l, 16, 0, 0);
}

// ---------------- small utility kernels ----------------

__global__ void k_zero(int* cnt) {
  if (threadIdx.x < E_) cnt[threadIdx.x] = 0;
}

// batched transpose + f32->bf16 (single): dst[z][C][R] = bf16(src[z][R][C])
__global__ __launch_bounds__(256) void k_transpose(const float* __restrict__ src,
                                                   u16* __restrict__ dst, int R, int C) {
  __shared__ u16 tile[32][33];
  int c0 = blockIdx.x * 32, r0 = blockIdx.y * 32;
  size_t zo = (size_t)blockIdx.z * (size_t)R * (size_t)C;
  int tx = threadIdx.x, ty = threadIdx.y;
  #pragma unroll
  for (int i = ty; i < 32; i += 8) {
    int r = r0 + i, cc = c0 + tx;
    float v = (r < R && cc < C) ? src[zo + (size_t)r * C + cc] : 0.f;
    tile[i][tx] = f2b(v);
  }
  __syncthreads();
  #pragma unroll
  for (int i = ty; i < 32; i += 8) {
    int cc = c0 + i, r = r0 + tx;
    if (cc < C && r < R) dst[zo + (size_t)cc * R + r] = tile[tx][i];
  }
}

// transpose + split f32 -> hi/lo bf16: dsth/dstl[C][R] = split(src[R][C])
__global__ __launch_bounds__(256) void k_split_transpose(const float* __restrict__ src,
                                                         u16* __restrict__ dsth,
                                                         u16* __restrict__ dstl,
                                                         int R, int C) {
  __shared__ float tile[32][33];
  int c0 = blockIdx.x * 32, r0 = blockIdx.y * 32;
  int tx = threadIdx.x, ty = threadIdx.y;
  #pragma unroll
  for (int i = ty; i < 32; i += 8) {
    int r = r0 + i, cc = c0 + tx;
    tile[i][tx] = (r < R && cc < C) ? src[(size_t)r * C + cc] : 0.f;
  }
  __syncthreads();
  #pragma unroll
  for (int i = ty; i < 32; i += 8) {
    int cc = c0 + i, r = r0 + tx;
    if (cc < C && r < R) {
      float v = tile[tx][i];
      u16 h = f2b(v);
      dsth[(size_t)cc * R + r] = h;
      dstl[(size_t)cc * R + r] = f2b(v - b2f(h));
    }
  }
}

// concat bq|bk|bv -> bqkv[1536]
__global__ void k_prep_bias(const float* bq, const float* bk, const float* bv, float* bqkv) {
  int i = blockIdx.x * 256 + threadIdx.x;
  if (i < 1024) bqkv[i] = bq[i];
  else if (i < 1280) bqkv[i] = bk[i - 1024];
  else if (i < 1536) bqkv[i] = bv[i - 1280];
}

// LayerNorm over D=1024; optional fp32 out, bf16 out, hi/lo split out
__global__ __launch_bounds__(256) void k_ln(const float* __restrict__ x,
                                            const float* __restrict__ sc,
                                            const float* __restrict__ bi,
                                            float* __restrict__ of,
                                            u16* __restrict__ ob,
                                            u16* __restrict__ oh,
                                            u16* __restrict__ ol) {
  int t = blockIdx.x, tid = threadIdx.x;
  const float* row = x + (size_t)t * D_;
  float4 v = *(const float4*)&row[tid * 4];
  float s = v.x + v.y + v.z + v.w;
  float ss = v.x * v.x + v.y * v.y + v.z * v.z + v.w * v.w;
  #pragma unroll
  for (int off = 32; off > 0; off >>= 1) {
    s += __shfl_xor(s, off);
    ss += __shfl_xor(ss, off);
  }
  __shared__ float red[8];
  if ((tid & 63) == 0) { red[(tid >> 6) * 2] = s; red[(tid >> 6) * 2 + 1] = ss; }
  __syncthreads();
  float S = red[0] + red[2] + red[4] + red[6];
  float SS = red[1] + red[3] + red[5] + red[7];
  float mu = S * (1.f / D_);
  float var = SS * (1.f / D_) - mu * mu;
  float rs = rsqrtf(var + 1e-6f);
  float4 scv = *(const float4*)&sc[tid * 4];
  float4 biv = *(const float4*)&bi[tid * 4];
  float o[4];
  o[0] = (v.x - mu) * rs * scv.x + biv.x;
  o[1] = (v.y - mu) * rs * scv.y + biv.y;
  o[2] = (v.z - mu) * rs * scv.z + biv.z;
  o[3] = (v.w - mu) * rs * scv.w + biv.w;
  size_t base = (size_t)t * D_ + tid * 4;
  if (of) *(float4*)&of[base] = make_float4(o[0], o[1], o[2], o[3]);
  if (ob) {
    ushort4 u;
    u.x = f2b(o[0]); u.y = f2b(o[1]); u.z = f2b(o[2]); u.w = f2b(o[3]);
    *(ushort4*)&ob[base] = u;
  }
  if (oh) {
    ushort4 uh, ulv;
    #pragma unroll
    for (int i = 0; i < 4; ++i) {
      u16 h = f2b(o[i]);
      u16 lo = f2b(o[i] - b2f(h));
      ((u16*)&uh)[i] = h;
      ((u16*)&ulv)[i] = lo;
    }
    *(ushort4*)&oh[base] = uh;
    *(ushort4*)&ol[base] = ulv;
  }
}

// ---------------- split-bf16 MFMA GEMM ----------------
// C[M,N] = (Ah+Al)[M,K] @ (Bh+Bl)[N,K]^T + bias  (3-term MFMA: hh + hl + lh)
// OUTMODE 0: write Ch/Cl (hi/lo bf16).  OUTMODE 1: write Cf = fp32 + res.
template <int OUTMODE>
__global__ __launch_bounds__(256) void k_gemm_split(const u16* __restrict__ Ah,
                                                    const u16* __restrict__ Al,
                                                    const u16* __restrict__ Bh,
                                                    const u16* __restrict__ Bl,
                                                    const float* __restrict__ bias,
                                                    const float* __restrict__ res,
                                                    u16* __restrict__ Ch,
                                                    u16* __restrict__ Cl,
                                                    float* __restrict__ Cf,
                                                    int M, int N, int K) {
  __shared__ __align__(16) u16 Ash[128 * 32], Asl[128 * 32];
  __shared__ __align__(16) u16 Bsh[128 * 32], Bsl[128 * 32];
  int tid = threadIdx.x, w = tid >> 6, l = tid & 63;
  int quad = l >> 4, l15 = l & 15;
  int m0 = blockIdx.x * 128, n0 = blockIdx.y * 128;
  int koff = (l & 3) * 8;
  const u16 *aph[2], *apl[2], *bph[2], *bpl[2];
  #pragma unroll
  for (int c = 0; c < 2; ++c) {
    int chunk = c * 4 + w;
    int row = m0 + chunk * 16 + (l >> 2);
    aph[c] = Ah + (size_t)row * K + koff;
    apl[c] = Al + (size_t)row * K + koff;
    int nrow = n0 + chunk * 16 + (l >> 2);
    bph[c] = Bh + (size_t)nrow * K + koff;
    bpl[c] = Bl + (size_t)nrow * K + koff;
  }
  f32x4 acc[4][4] = {};
  int wm = (w & 1) * 64, wn = (w >> 1) * 64;
  for (int k0 = 0; k0 < K; k0 += 32) {
    __syncthreads();
    #pragma unroll
    for (int c = 0; c < 2; ++c) {
      gload16(aph[c] + k0, &Ash[(c * 4 + w) * 512]);
      gload16(apl[c] + k0, &Asl[(c * 4 + w) * 512]);
      gload16(bph[c] + k0, &Bsh[(c * 4 + w) * 512]);
      gload16(bpl[c] + k0, &Bsl[(c * 4 + w) * 512]);
    }
    __syncthreads();
    bf16x8 ah[4], al_[4], bh[4], bl_[4];
    #pragma unroll
    for (int i = 0; i < 4; ++i) {
      ah[i] = *(const bf16x8*)&Ash[(wm + i * 16 + l15) * 32 + quad * 8];
      al_[i] = *(const bf16x8*)&Asl[(wm + i * 16 + l15) * 32 + quad * 8];
    }
    #pragma unroll
    for (int j = 0; j < 4; ++j) {
      bh[j] = *(const bf16x8*)&Bsh[(wn + j * 16 + l15) * 32 + quad * 8];
      bl_[j] = *(const bf16x8*)&Bsl[(wn + j * 16 + l15) * 32 + quad * 8];
    }
    #pragma unroll
    for (int i = 0; i < 4; ++i)
      #pragma unroll
      for (int j = 0; j < 4; ++j) {
        acc[i][j] = __builtin_amdgcn_mfma_f32_16x16x32_bf16(ah[i], bh[j], acc[i][j], 0, 0, 0);
        acc[i][j] = __builtin_amdgcn_mfma_f32_16x16x32_bf16(ah[i], bl_[j], acc[i][j], 0, 0, 0);
        acc[i][j] = __builtin_amdgcn_mfma_f32_16x16x32_bf16(al_[i], bh[j], acc[i][j], 0, 0, 0);
      }
  }
  #pragma unroll
  for (int i = 0; i < 4; ++i) {
    #pragma unroll
    for (int j = 0; j < 4; ++j) {
      int gn = n0 + wn + j * 16 + l15;
      float bv = bias[gn];
      #pragma unroll
      for (int r = 0; r < 4; ++r) {
        int gm = m0 + wm + i * 16 + quad * 4 + r;
        size_t idx = (size_t)gm * N + gn;
        float v = acc[i][j][r] + bv;
        if (OUTMODE == 0) {
          u16 h = f2b(v);
          Ch[idx] = h;
          Cl[idx] = f2b(v - b2f(h));
        } else {
          Cf[idx] = v + res[idx];
        }
      }
    }
  }
}

// ---------------- MFMA flash attention with session-delta decay ----------------
#define AP 72  // padded u16 row stride for LDS tiles
__global__ __launch_bounds__(256) void k_attn_mfma(const u16* __restrict__ qkv_h,
                                                   const u16* __restrict__ qkv_l,
                                                   const float* __restrict__ sd,
                                                   const float* __restrict__ td,
                                                   u16* __restrict__ o_h,
                                                   u16* __restrict__ o_l) {
  __shared__ __align__(16) u16 Qh[64 * AP], Ql[64 * AP];
  __shared__ __align__(16) u16 Kh[64 * AP], Kl[64 * AP];
  __shared__ __align__(16) u16 Vth[64 * AP], Vtl[64 * AP];
  __shared__ __align__(16) u16 Ph[4][16 * AP], Pl[4][16 * AP];
  __shared__ float sds[64];
  int tid = threadIdx.x, w = tid >> 6, l = tid & 63;
  int quad = l >> 4, l15 = l & 15;
  int q0 = blockIdx.x * 64, h = blockIdx.y, b = blockIdx.z;
  int g = h >> 2;
  int r = tid >> 2, cb = (tid & 3) * 16;

  {
    const u16* gq_h = qkv_h + (size_t)(b * S_ + q0 + r) * 1536 + h * HD_ + cb;
    const u16* gq_l = qkv_l + (size_t)(b * S_ + q0 + r) * 1536 + h * HD_ + cb;
    #pragma unroll
    for (int c = 0; c < 4; ++c) {
      *(ushort4*)&Qh[r * AP + cb + c * 4] = *(const ushort4*)&gq_h[c * 4];
      *(ushort4*)&Ql[r * AP + cb + c * 4] = *(const ushort4*)&gq_l[c * 4];
    }
  }
  __syncthreads();
  bf16x8 aqh[2], aql[2];
  #pragma unroll
  for (int kk = 0; kk < 2; ++kk) {
    aqh[kk] = *(const bf16x8*)&Qh[(w * 16 + l15) * AP + kk * 32 + quad * 8];
    aql[kk] = *(const bf16x8*)&Ql[(w * 16 + l15) * AP + kk * 32 + quad * 8];
  }
  float sp = log1pf(__expf(td[h]));
  float dq[4];
  #pragma unroll
  for (int i = 0; i < 4; ++i) dq[i] = sd[b * S_ + q0 + w * 16 + quad * 4 + i];

  float mr[4], lr[4];
  f32x4 oa[4] = {};
  #pragma unroll
  for (int i = 0; i < 4; ++i) { mr[i] = -3.0e38f; lr[i] = 0.f; }

  for (int s0 = 0; s0 < S_; s0 += 64) {
    const u16* gk_h = qkv_h + (size_t)(b * S_ + s0 + r) * 1536 + 1024 + g * HD_ + cb;
    const u16* gk_l = qkv_l + (size_t)(b * S_ + s0 + r) * 1536 + 1024 + g * HD_ + cb;
    const u16* gv_h = qkv_h + (size_t)(b * S_ + s0 + r) * 1536 + 1280 + g * HD_ + cb;
    const u16* gv_l = qkv_l + (size_t)(b * S_ + s0 + r) * 1536 + 1280 + g * HD_ + cb;
    ushort4 kh4[4], kl4[4];
    u16 vh[16], vl[16];
    #pragma unroll
    for (int c = 0; c < 4; ++c) {
      kh4[c] = *(const ushort4*)&gk_h[c * 4];
      kl4[c] = *(const ushort4*)&gk_l[c * 4];
      *(ushort4*)&vh[c * 4] = *(const ushort4*)&gv_h[c * 4];
      *(ushort4*)&vl[c * 4] = *(const ushort4*)&gv_l[c * 4];
    }
    __syncthreads();
    #pragma unroll
    for (int c = 0; c < 4; ++c) {
      *(ushort4*)&Kh[r * AP + cb + c * 4] = kh4[c];
      *(ushort4*)&Kl[r * AP + cb + c * 4] = kl4[c];
    }
    #pragma unroll
    for (int i = 0; i < 16; ++i) {
      Vth[(cb + i) * AP + r] = vh[i];
      Vtl[(cb + i) * AP + r] = vl[i];
    }
    if (tid < 64) sds[tid] = sd[b * S_ + s0 + tid];
    __syncthreads();

    f32x4 sc[4] = {};
    #pragma unroll
    for (int j = 0; j < 4; ++j) {
      #pragma unroll
      for (int kk = 0; kk < 2; ++kk) {
        bf16x8 bkh = *(const bf16x8*)&Kh[(j * 16 + l15) * AP + kk * 32 + quad * 8];
        bf16x8 bkl = *(const bf16x8*)&Kl[(j * 16 + l15) * AP + kk * 32 + quad * 8];
        sc[j] = __builtin_amdgcn_mfma_f32_16x16x32_bf16(aqh[kk], bkh, sc[j], 0, 0, 0);
        sc[j] = __builtin_amdgcn_mfma_f32_16x16x32_bf16(aqh[kk], bkl, sc[j], 0, 0, 0);
        sc[j] = __builtin_amdgcn_mfma_f32_16x16x32_bf16(aql[kk], bkh, sc[j], 0, 0, 0);
      }
    }
    float ds_[4];
    #pragma unroll
    for (int j = 0; j < 4; ++j) ds_[j] = sds[j * 16 + l15];
    float s_[4][4];
    #pragma unroll
    for (int j = 0; j < 4; ++j)
      #pragma unroll
      for (int i = 0; i < 4; ++i)
        s_[j][i] = sc[j][i] * 0.125f - sp * fabsf(dq[i] - ds_[j]);
    float mx[4];
    #pragma unroll
    for (int i = 0; i < 4; ++i)
      mx[i] = fmaxf(fmaxf(s_[0][i], s_[1][i]), fmaxf(s_[2][i], s_[3][i]));
    #pragma unroll
    for (int d = 1; d < 16; d <<= 1)
      #pragma unroll
      for (int i = 0; i < 4; ++i) mx[i] = fmaxf(mx[i], __shfl_xor(mx[i], d));
    float al[4], rsum[4], p[4][4];
    #pragma unroll
    for (int i = 0; i < 4; ++i) {
      float mn = fmaxf(mr[i], mx[i]);
      al[i] = __expf(mr[i] - mn);
      mr[i] = mn;
      rsum[i] = 0.f;
      #pragma unroll
      for (int j = 0; j < 4; ++j) { p[j][i] = __expf(s_[j][i] - mn); rsum[i] += p[j][i]; }
    }
    #pragma unroll
    for (int d = 1; d < 16; d <<= 1)
      #pragma unroll
      for (int i = 0; i < 4; ++i) rsum[i] += __shfl_xor(rsum[i], d);
    #pragma unroll
    for (int i = 0; i < 4; ++i) {
      lr[i] = lr[i] * al[i] + rsum[i];
      #pragma unroll
      for (int j = 0; j < 4; ++j) oa[j][i] *= al[i];
    }
    #pragma unroll
    for (int j = 0; j < 4; ++j)
      #pragma unroll
      for (int i = 0; i < 4; ++i) {
        float pv = p[j][i];
        u16 hv = f2b(pv);
        Ph[w][(quad * 4 + i) * AP + j * 16 + l15] = hv;
        Pl[w][(quad * 4 + i) * AP + j * 16 + l15] = f2b(pv - b2f(hv));
      }
    bf16x8 aph[2], apl[2];
    #pragma unroll
    for (int kk = 0; kk < 2; ++kk) {
      aph[kk] = *(const bf16x8*)&Ph[w][l15 * AP + kk * 32 + quad * 8];
      apl[kk] = *(const bf16x8*)&Pl[w][l15 * AP + kk * 32 + quad * 8];
    }
    #pragma unroll
    for (int j = 0; j < 4; ++j) {
      #pragma unroll
      for (int kk = 0; kk < 2; ++kk) {
        bf16x8 bvh = *(const bf16x8*)&Vth[(j * 16 + l15) * AP + kk * 32 + quad * 8];
        bf16x8 bvl = *(const bf16x8*)&Vtl[(j * 16 + l15) * AP + kk * 32 + quad * 8];
        oa[j] = __builtin_amdgcn_mfma_f32_16x16x32_bf16(aph[kk], bvh, oa[j], 0, 0, 0);
        oa[j] = __builtin_amdgcn_mfma_f32_16x16x32_bf16(aph[kk], bvl, oa[j], 0, 0, 0);
        oa[j] = __builtin_amdgcn_mfma_f32_16x16x32_bf16(apl[kk], bvh, oa[j], 0, 0, 0);
      }
    }
  }
  #pragma unroll
  for (int i = 0; i < 4; ++i) {
    float inv = 1.f / lr[i];
    int q = b * S_ + q0 + w * 16 + quad * 4 + i;
    #pragma unroll
    for (int j = 0; j < 4; ++j) {
      float ov = oa[j][i] * inv;
      size_t idx = (size_t)q * (H_ * HD_) + h * HD_ + j * 16 + l15;
      u16 hv = f2b(ov);
      o_h[idx] = hv;
      o_l[idx] = f2b(ov - b2f(hv));
    }
  }
}

// ---------------- router ----------------
__global__ __launch_bounds__(256) void k_router(const float* __restrict__ xn2,
                                                const float* __restrict__ rw,
                                                const float* __restrict__ rb,
                                                int* __restrict__ eidx, int* __restrict__ epos,
                                                float* __restrict__ ew, int* __restrict__ cnt,
                                                int* __restrict__ list) {
  int t = blockIdx.x * 4 + (threadIdx.x >> 6);
  int l = threadIdx.x & 63;
  const float* row = xn2 + (size_t)t * D_;
  float acc[8];
  #pragma unroll
  for (int e = 0; e < 8; ++e) acc[e] = 0.f;
  for (int i = 0; i < 16; ++i) {
    int d = l + i * 64;
    float xv = row[d];
    float4 w0 = *(const float4*)&rw[d * 8 + 0];
    float4 w1 = *(const float4*)&rw[d * 8 + 4];
    acc[0] = fmaf(xv, w0.x, acc[0]); acc[1] = fmaf(xv, w0.y, acc[1]);
    acc[2] = fmaf(xv, w0.z, acc[2]); acc[3] = fmaf(xv, w0.w, acc[3]);
    acc[4] = fmaf(xv, w1.x, acc[4]); acc[5] = fmaf(xv, w1.y, acc[5]);
    acc[6] = fmaf(xv, w1.z, acc[6]); acc[7] = fmaf(xv, w1.w, acc[7]);
  }
  #pragma unroll
  for (int off = 32; off > 0; off >>= 1)
    #pragma unroll
    for (int e = 0; e < 8; ++e) acc[e] += __shfl_xor(acc[e], off);
  if (l == 0) {
    float lg[8];
    #pragma unroll
    for (int e = 0; e < 8; ++e) lg[e] = acc[e] + rb[e];
    int i1 = 0;
    #pragma unroll
    for (int e = 1; e < 8; ++e) if (lg[e] > lg[i1]) i1 = e;
    int i2 = (i1 == 0) ? 1 : 0;
    #pragma unroll
    for (int e = 0; e < 8; ++e) if (e != i1 && lg[e] > lg[i2]) i2 = e;
    float wa = 1.f / (1.f + __expf(lg[i2] - lg[i1]));
    float wb = 1.f - wa;
    int pa = atomicAdd(&cnt[i1], 1);
    int pb = atomicAdd(&cnt[i2], 1);
    list[i1 * T_ + pa] = t;
    list[i2 * T_ + pb] = t;
    eidx[2 * t] = i1; eidx[2 * t + 1] = i2;
    epos[2 * t] = pa; epos[2 * t + 1] = pb;
    ew[2 * t] = wa; ew[2 * t + 1] = wb;
  }
}

// offs[0..7] = slot prefix; offs[8..15] = 128-row tile prefix; offs[16] = total tiles
__global__ void k_offsets(const int* __restrict__ cnt, int* __restrict__ offs) {
  if (threadIdx.x == 0 && blockIdx.x == 0) {
    int tot = 0, ttot = 0;
    for (int e = 0; e < E_; ++e) {
      offs[e] = tot; tot += cnt[e];
      offs[8 + e] = ttot; ttot += (cnt[e] + 127) >> 7;
    }
    offs[16] = ttot;
  }
}

// ---------------- gather A rows densely per expert slot ----------------
// dst[offs[e]+i][:] = src[list[e*T_+i]][:]  — turns the MoE GEMM's random
// row gather into streaming loads inside the latency-critical loop.
__global__ __launch_bounds__(128) void k_gather(const u16* __restrict__ src,
                                                const int* __restrict__ offs,
                                                const int* __restrict__ list,
                                                u16* __restrict__ dst) {
  int s = blockIdx.x;  // slot 0 .. 2*T_-1
  int e = 0;
  #pragma unroll
  for (int i = 1; i < E_; ++i) e = (s >= offs[i]) ? i : e;
  int tok = list[e * T_ + (s - offs[e])];
  int l = threadIdx.x;  // 128 threads x 8 u16 = 1024
  ushort4 a = *(const ushort4*)&src[(size_t)tok * D_ + l * 8];
  ushort4 b = *(const ushort4*)&src[(size_t)tok * D_ + l * 8 + 4];
  *(ushort4*)&dst[(size_t)s * D_ + l * 8] = a;
  *(ushort4*)&dst[(size_t)s * D_ + l * 8 + 4] = b;
}

// ---------------- bf16 MFMA GEMM for MoE ----------------
// Dense 1-D work grid: wid -> (expert tile tx, n-tile ny) via device tile
// table (meta[8..15] tile prefix, meta[16] = total tiles).  XCD-bijective
// swizzle gives each XCD a contiguous chunk (A-panel L2 reuse).
// 3-buffer LDS, depth-2 prefetch, counted vmcnt, raw s_barrier, setprio.
// MODE 0: h[slot] = gelu(A[slot] @ w1t[e]^T + b1[e]) -> u16
// MODE 1: y[slot] = h[slot] @ w2t[e]^T + b2[e]       -> u16
template <int MODE, int LOGNY>
__global__ __launch_bounds__(256) void k_moe_gemm(const u16* __restrict__ Ab,
                                                  const u16* __restrict__ Wt,
                                                  const float* __restrict__ bias,
                                                  u16* __restrict__ outU,
                                                  const int* __restrict__ cnt,
                                                  const int* __restrict__ meta,
                                                  int N, int K) {
  // bijective XCD swizzle (gridDim.x % 8 == 0): XCD k gets wids [k*q,(k+1)*q)
  int q = gridDim.x >> 3;
  int wid = (blockIdx.x & 7) * q + (blockIdx.x >> 3);
  int tx = wid >> LOGNY;
  int ny = wid & ((1 << LOGNY) - 1);
  if (tx >= meta[16]) return;
  int e = 0;
  #pragma unroll
  for (int i = 1; i < E_; ++i) e = (tx >= meta[8 + i]) ? i : e;
  int myM = cnt[e];
  int m0 = (tx - meta[8 + e]) * 128;
  int n0 = ny * 128;
  __shared__ __align__(16) u16 As[3][128 * 32];
  __shared__ __align__(16) u16 Bs[3][128 * 32];
  int tid = threadIdx.x, w = tid >> 6, l = tid & 63;
  int quad = l >> 4, l15 = l & 15;
  int koff = (l & 3) * 8;
  const u16* ap[2];
  const u16* bp[2];
  #pragma unroll
  for (int c = 0; c < 2; ++c) {
    int chunk = c * 4 + w;
    int r = m0 + chunk * 16 + (l >> 2);
    int rr = (r < myM) ? r : (myM - 1);
    ap[c] = Ab + (size_t)(meta[e] + rr) * K + koff;
    int nrow = n0 + chunk * 16 + (l >> 2);
    bp[c] = Wt + (size_t)e * N * K + (size_t)nrow * K + koff;
  }
  f32x4 acc[4][4] = {};
  int wm = (w & 1) * 64, wn = (w >> 1) * 64;
  int nsteps = K >> 5;  // 32 (MODE 0) or 128 (MODE 1), always >= 2
  // prologue: stage K-tiles 0 and 1 into buffers 0 and 1
  #pragma unroll
  for (int c = 0; c < 2; ++c) {
    gload16(ap[c], &As[0][(c * 4 + w) * 512]);
    gload16(bp[c], &Bs[0][(c * 4 + w) * 512]);
  }
  #pragma unroll
  for (int c = 0; c < 2; ++c) {
    gload16(ap[c] + 32, &As[1][(c * 4 + w) * 512]);
    gload16(bp[c] + 32, &Bs[1][(c * 4 + w) * 512]);
  }
  int cur = 0, stg = 2;
  for (int it = 0; it < nsteps - 1; ++it) {
    // wait until stage(it) has landed; stage(it+1) (4 loads) stays in flight
    asm volatile("s_waitcnt vmcnt(4)" ::: "memory");
    asm volatile("s_barrier" ::: "memory");
    if (it < nsteps - 2) {
      int k0 = (it + 2) << 5;
      #pragma unroll
      for (int c = 0; c < 2; ++c) {
        gload16(ap[c] + k0, &As[stg][(c * 4 + w) * 512]);
        gload16(bp[c] + k0, &Bs[stg][(c * 4 + w) * 512]);
      }
    }
    bf16x8 af[4], bfv[4];
    #pragma unroll
    for (int i = 0; i < 4; ++i)
      af[i] = *(const bf16x8*)&As[cur][(wm + i * 16 + l15) * 32 + quad * 8];
    #pragma unroll
    for (int j = 0; j < 4; ++j)
      bfv[j] = *(const bf16x8*)&Bs[cur][(wn + j * 16 + l15) * 32 + quad * 8];
    __builtin_amdgcn_s_setprio(1);
    #pragma unroll
    for (int i = 0; i < 4; ++i)
      #pragma unroll
      for (int j = 0; j < 4; ++j)
        acc[i][j] = __builtin_amdgcn_mfma_f32_16x16x32_bf16(af[i], bfv[j], acc[i][j], 0, 0, 0);
    __builtin_amdgcn_s_setprio(0);
    cur = (cur == 2) ? 0 : cur + 1;
    stg = (stg == 2) ? 0 : stg + 1;
  }
  // tail iteration: only the last stage is outstanding — drain it
  asm volatile("s_waitcnt vmcnt(0)" ::: "memory");
  asm volatile("s_barrier" ::: "memory");
  {
    bf16x8 af[4], bfv[4];
    #pragma unroll
    for (int i = 0; i < 4; ++i)
      af[i] = *(const bf16x8*)&As[cur][(wm + i * 16 + l15) * 32 + quad * 8];
    #pragma unroll
    for (int j = 0; j < 4; ++j)
      bfv[j] = *(const bf16x8*)&Bs[cur][(wn + j * 16 + l15) * 32 + quad * 8];
    __builtin_amdgcn_s_setprio(1);
    #pragma unroll
    for (int i = 0; i < 4; ++i)
      #pragma unroll
      for (int j = 0; j < 4; ++j)
        acc[i][j] = __builtin_amdgcn_mfma_f32_16x16x32_bf16(af[i], bfv[j], acc[i][j], 0, 0, 0);
    __builtin_amdgcn_s_setprio(0);
  }
  const float* bptr = bias + (size_t)e * N;
  #pragma unroll
  for (int i = 0; i < 4; ++i) {
    #pragma unroll
    for (int j = 0; j < 4; ++j) {
      int gn = n0 + wn + j * 16 + l15;
      float bv = bptr[gn];
      #pragma unroll
      for (int r = 0; r < 4; ++r) {
        int gm = m0 + wm + i * 16 + quad * 4 + r;
        if (gm < myM) {
          float vv = acc[i][j][r] + bv;
          if (MODE == 0) vv = gelu_t(vv);
          outU[(size_t)(meta[e] + gm) * N + gn] = f2b(vv);
        }
      }
    }
  }
}

// ---------------- final combine ----------------
__global__ __launch_bounds__(256) void k_combine(const float* __restrict__ x1,
                                                 const u16* __restrict__ y,
                                                 const int* __restrict__ eidx,
                                                 const int* __restrict__ epos,
                                                 const float* __restrict__ ew,
                                                 const int* __restrict__ offs,
                                                 float* __restrict__ out) {
  int t = blockIdx.x, tid = threadIdx.x;
  int e0 = eidx[2 * t], e1 = eidx[2 * t + 1];
  int s0 = offs[e0] + epos[2 * t];
  int s1 = offs[e1] + epos[2 * t + 1];
  float w0 = ew[2 * t], w1 = ew[2 * t + 1];
  int d = tid * 4;
  float4 a = *(const float4*)&x1[(size_t)t * D_ + d];
  ushort4 y0 = *(const ushort4*)&y[(size_t)s0 * D_ + d];
  ushort4 y1 = *(const ushort4*)&y[(size_t)s1 * D_ + d];
  float4 r;
  r.x = a.x + w0 * b2f(y0.x) + w1 * b2f(y1.x);
  r.y = a.y + w0 * b2f(y0.y) + w1 * b2f(y1.y);
  r.z = a.z + w0 * b2f(y0.z) + w1 * b2f(y1.z);
  r.w = a.w + w0 * b2f(y0.w) + w1 * b2f(y1.w);
  *(float4*)&out[(size_t)t * D_ + d] = r;
}

// ---------------- launch ----------------
extern "C" void kernel_launch(void* const* d_in, const int* in_sizes, int n_in,
                              void* d_out, int out_size, void* d_ws, size_t ws_size,
                              hipStream_t stream) {
  (void)in_sizes; (void)n_in; (void)out_size; (void)ws_size;
  const float* x    = (const float*)d_in[0];
  const float* sd   = (const float*)d_in[1];
  const float* ln1s = (const float*)d_in[2];
  const float* ln1b = (const float*)d_in[3];
  const float* wq   = (const float*)d_in[4];
  const float* bq   = (const float*)d_in[5];
  const float* wk   = (const float*)d_in[6];
  const float* bk   = (const float*)d_in[7];
  const float* wv   = (const float*)d_in[8];
  const float* bv   = (const float*)d_in[9];
  const float* wo   = (const float*)d_in[10];
  const float* bo   = (const float*)d_in[11];
  const float* td   = (const float*)d_in[12];
  const float* ln2s = (const float*)d_in[13];
  const float* ln2b = (const float*)d_in[14];
  const float* rw   = (const float*)d_in[15];
  const float* rb   = (const float*)d_in[16];
  const float* w1   = (const float*)d_in[17];
  const float* b1   = (const float*)d_in[18];
  const float* w2   = (const float*)d_in[19];
  const float* b2   = (const float*)d_in[20];
  float* out = (float*)d_out;

  const size_t MBy = 1024ull * 1024ull;
  char* ws = (char*)d_ws;
  u16*   w1t   = (u16*)(ws + 0);          // 64MB   [prep -> moe1]
  u16*   w2t   = (u16*)(ws + 64 * MBy);   // 64MB   [prep -> moe2]
  u16*   hb    = (u16*)(ws + 128 * MBy);  // 64MB   [moe1 -> moe2]
  float* xn2   = (float*)(ws + 128 * MBy);// 16MB   aliases hb (dead before moe1)
  u16*   wqkvTh= (u16*)(ws + 192 * MBy);  // 3MB
  u16*   wqkvTl= (u16*)(ws + 195 * MBy);  // 3MB
  u16*   woTh  = (u16*)(ws + 198 * MBy);  // 2MB
  u16*   woTl  = (u16*)(ws + 200 * MBy);  // 2MB
  float* bqkv  = (float*)(ws + 202 * MBy);// 6KB
  int*   eidx  = (int*)(ws + 202 * MBy + 65536);
  int*   epos  = eidx + 2 * T_;
  float* ew    = (float*)(epos + 2 * T_);
  int*   list  = (int*)(ew + 2 * T_);
  int*   cnt   = list + E_ * T_;
  int*   offs  = cnt + E_;               // 17 ints: slots[8] | tiles[8] | ttot
  u16*   xn_h  = (u16*)(ws + 203 * MBy);  // 8MB    [ln1 -> qkv gemm]
  u16*   xn_l  = (u16*)(ws + 211 * MBy);  // 8MB
  u16*   xn2b  = (u16*)(ws + 203 * MBy);  // 8MB    aliases xn_h (dead)
  u16*   qkv_h = (u16*)(ws + 219 * MBy);  // 13MB   [qkv -> attn]
  u16*   qkv_l = (u16*)(ws + 232 * MBy);  // 13MB
  u16*   yb    = (u16*)(ws + 219 * MBy);  // 16MB   aliases qkv (dead after attn)
  u16*   o_h   = (u16*)(ws + 245 * MBy);  // 8MB    [attn -> outproj]
  u16*   o_l   = (u16*)(ws + 253 * MBy);  // 8MB
  u16*   aprime= (u16*)(ws + 245 * MBy);  // 16MB   aliases o_h/o_l (dead after outproj)
  float* x1    = (float*)(ws + 261 * MBy);// 16MB   [outproj -> combine]

  k_zero<<<1, 64, 0, stream>>>(cnt);
  k_transpose<<<dim3(F_ / 32, D_ / 32, E_), dim3(32, 8), 0, stream>>>(w1, w1t, D_, F_);
  k_transpose<<<dim3(D_ / 32, F_ / 32, E_), dim3(32, 8), 0, stream>>>(w2, w2t, F_, D_);
  k_split_transpose<<<dim3(1024 / 32, 1024 / 32), dim3(32, 8), 0, stream>>>(wq, wqkvTh, wqkvTl, 1024, 1024);
  k_split_transpose<<<dim3(256 / 32, 1024 / 32), dim3(32, 8), 0, stream>>>(wk, wqkvTh + 1024 * 1024, wqkvTl + 1024 * 1024, 1024, 256);
  k_split_transpose<<<dim3(256 / 32, 1024 / 32), dim3(32, 8), 0, stream>>>(wv, wqkvTh + 1280 * 1024, wqkvTl + 1280 * 1024, 1024, 256);
  k_split_transpose<<<dim3(1024 / 32, 1024 / 32), dim3(32, 8), 0, stream>>>(wo, woTh, woTl, 1024, 1024);
  k_prep_bias<<<6, 256, 0, stream>>>(bq, bk, bv, bqkv);

  k_ln<<<T_, 256, 0, stream>>>(x, ln1s, ln1b, nullptr, nullptr, xn_h, xn_l);

  k_gemm_split<0><<<dim3(T_ / 128, 1536 / 128), 256, 0, stream>>>(
      xn_h, xn_l, wqkvTh, wqkvTl, bqkv, nullptr, qkv_h, qkv_l, nullptr, T_, 1536, 1024);

  k_attn_mfma<<<dim3(S_ / 64, H_, B_), 256, 0, stream>>>(qkv_h, qkv_l, sd, td, o_h, o_l);

  k_gemm_split<1><<<dim3(T_ / 128, 1024 / 128), 256, 0, stream>>>(
      o_h, o_l, woTh, woTl, bo, x, nullptr, nullptr, x1, T_, 1024, 1024);

  k_ln<<<T_, 256, 0, stream>>>(x1, ln2s, ln2b, xn2, xn2b, nullptr, nullptr);

  k_router<<<T_ / 4, 256, 0, stream>>>(xn2, rw, rb, eidx, epos, ew, cnt, list);
  k_offsets<<<1, 64, 0, stream>>>(cnt, offs);
  k_gather<<<2 * T_, 128, 0, stream>>>(xn2b, offs, list, aprime);

  // dense 1-D grids: max 72 M-tiles (8192 slots / 128 + 8 partials)
  k_moe_gemm<0, 5><<<dim3(72 * 32), 256, 0, stream>>>(aprime, w1t, b1, hb, cnt, offs, F_, D_);
  k_moe_gemm<1, 3><<<dim3(72 * 8), 256, 0, stream>>>(hb, w2t, b2, yb, cnt, offs, D_, F_);

  k_combine<<<T_, 256, 0, stream>>>(x1, yb, eidx, epos, ew, offs, out);
}

// Round 4
// 1064.081 us; speedup vs baseline: 1.5301x; 1.0347x over previous
//
#include <hip/hip_runtime.h>
#include <cstdint>
#include <cstddef>

typedef unsigned short u16;
typedef __bf16 bf16x8 __attribute__((ext_vector_type(8)));
typedef float f32x4 __attribute__((ext_vector_type(4)));

#define B_ 2
#define S_ 2048
#define D_ 1024
#define H_ 16
#define G_ 4
#define HD_ 64
#define E_ 8
#define F_ 4096
#define T_ 4096

__device__ __forceinline__ u16 f2b(float f) {
  unsigned u = __float_as_uint(f);
  return (u16)((u + 0x7fffu + ((u >> 16) & 1u)) >> 16);
}
__device__ __forceinline__ float b2f(u16 h) {
  return __uint_as_float(((unsigned)h) << 16);
}

__device__ __forceinline__ float gelu_t(float x) {
  float u = 0.7978845608028654f * (x + 0.044715f * x * x * x);
  float t = 1.f - 2.f / (__expf(2.f * u) + 1.f);
  return 0.5f * x * (1.f + t);
}

__device__ __forceinline__ void gload16(const void* g, void* l) {
  __builtin_amdgcn_global_load_lds((__attribute__((address_space(1))) void*)g,
                                   (__attribute__((address_space(3))) void*)l, 16, 0, 0);
}

// ---------------- small utility kernels ----------------

__global__ void k_zero(int* cnt) {
  if (threadIdx.x < E_) cnt[threadIdx.x] = 0;
}

// batched transpose + f32->bf16 (single): dst[z][C][R] = bf16(src[z][R][C])
__global__ __launch_bounds__(256) void k_transpose(const float* __restrict__ src,
                                                   u16* __restrict__ dst, int R, int C) {
  __shared__ u16 tile[32][33];
  int c0 = blockIdx.x * 32, r0 = blockIdx.y * 32;
  size_t zo = (size_t)blockIdx.z * (size_t)R * (size_t)C;
  int tx = threadIdx.x, ty = threadIdx.y;
  #pragma unroll
  for (int i = ty; i < 32; i += 8) {
    int r = r0 + i, cc = c0 + tx;
    float v = (r < R && cc < C) ? src[zo + (size_t)r * C + cc] : 0.f;
    tile[i][tx] = f2b(v);
  }
  __syncthreads();
  #pragma unroll
  for (int i = ty; i < 32; i += 8) {
    int cc = c0 + i, r = r0 + tx;
    if (cc < C && r < R) dst[zo + (size_t)cc * R + r] = tile[tx][i];
  }
}

// transpose + split f32 -> hi/lo bf16: dsth/dstl[C][R] = split(src[R][C])
__global__ __launch_bounds__(256) void k_split_transpose(const float* __restrict__ src,
                                                         u16* __restrict__ dsth,
                                                         u16* __restrict__ dstl,
                                                         int R, int C) {
  __shared__ float tile[32][33];
  int c0 = blockIdx.x * 32, r0 = blockIdx.y * 32;
  int tx = threadIdx.x, ty = threadIdx.y;
  #pragma unroll
  for (int i = ty; i < 32; i += 8) {
    int r = r0 + i, cc = c0 + tx;
    tile[i][tx] = (r < R && cc < C) ? src[(size_t)r * C + cc] : 0.f;
  }
  __syncthreads();
  #pragma unroll
  for (int i = ty; i < 32; i += 8) {
    int cc = c0 + i, r = r0 + tx;
    if (cc < C && r < R) {
      float v = tile[tx][i];
      u16 h = f2b(v);
      dsth[(size_t)cc * R + r] = h;
      dstl[(size_t)cc * R + r] = f2b(v - b2f(h));
    }
  }
}

// concat bq|bk|bv -> bqkv[1536]
__global__ void k_prep_bias(const float* bq, const float* bk, const float* bv, float* bqkv) {
  int i = blockIdx.x * 256 + threadIdx.x;
  if (i < 1024) bqkv[i] = bq[i];
  else if (i < 1280) bqkv[i] = bk[i - 1024];
  else if (i < 1536) bqkv[i] = bv[i - 1280];
}

// LayerNorm over D=1024; optional fp32 out, bf16 out, hi/lo split out
__global__ __launch_bounds__(256) void k_ln(const float* __restrict__ x,
                                            const float* __restrict__ sc,
                                            const float* __restrict__ bi,
                                            float* __restrict__ of,
                                            u16* __restrict__ ob,
                                            u16* __restrict__ oh,
                                            u16* __restrict__ ol) {
  int t = blockIdx.x, tid = threadIdx.x;
  const float* row = x + (size_t)t * D_;
  float4 v = *(const float4*)&row[tid * 4];
  float s = v.x + v.y + v.z + v.w;
  float ss = v.x * v.x + v.y * v.y + v.z * v.z + v.w * v.w;
  #pragma unroll
  for (int off = 32; off > 0; off >>= 1) {
    s += __shfl_xor(s, off);
    ss += __shfl_xor(ss, off);
  }
  __shared__ float red[8];
  if ((tid & 63) == 0) { red[(tid >> 6) * 2] = s; red[(tid >> 6) * 2 + 1] = ss; }
  __syncthreads();
  float S = red[0] + red[2] + red[4] + red[6];
  float SS = red[1] + red[3] + red[5] + red[7];
  float mu = S * (1.f / D_);
  float var = SS * (1.f / D_) - mu * mu;
  float rs = rsqrtf(var + 1e-6f);
  float4 scv = *(const float4*)&sc[tid * 4];
  float4 biv = *(const float4*)&bi[tid * 4];
  float o[4];
  o[0] = (v.x - mu) * rs * scv.x + biv.x;
  o[1] = (v.y - mu) * rs * scv.y + biv.y;
  o[2] = (v.z - mu) * rs * scv.z + biv.z;
  o[3] = (v.w - mu) * rs * scv.w + biv.w;
  size_t base = (size_t)t * D_ + tid * 4;
  if (of) *(float4*)&of[base] = make_float4(o[0], o[1], o[2], o[3]);
  if (ob) {
    ushort4 u;
    u.x = f2b(o[0]); u.y = f2b(o[1]); u.z = f2b(o[2]); u.w = f2b(o[3]);
    *(ushort4*)&ob[base] = u;
  }
  if (oh) {
    ushort4 uh, ulv;
    #pragma unroll
    for (int i = 0; i < 4; ++i) {
      u16 h = f2b(o[i]);
      u16 lo = f2b(o[i] - b2f(h));
      ((u16*)&uh)[i] = h;
      ((u16*)&ulv)[i] = lo;
    }
    *(ushort4*)&oh[base] = uh;
    *(ushort4*)&ol[base] = ulv;
  }
}

// ---------------- split-bf16 MFMA GEMM ----------------
// C[M,N] = (Ah+Al)[M,K] @ (Bh+Bl)[N,K]^T + bias  (3-term MFMA: hh + hl + lh)
// OUTMODE 0: write Ch/Cl (hi/lo bf16).  OUTMODE 1: write Cf = fp32 + res.
template <int OUTMODE>
__global__ __launch_bounds__(256) void k_gemm_split(const u16* __restrict__ Ah,
                                                    const u16* __restrict__ Al,
                                                    const u16* __restrict__ Bh,
                                                    const u16* __restrict__ Bl,
                                                    const float* __restrict__ bias,
                                                    const float* __restrict__ res,
                                                    u16* __restrict__ Ch,
                                                    u16* __restrict__ Cl,
                                                    float* __restrict__ Cf,
                                                    int M, int N, int K) {
  __shared__ __align__(16) u16 Ash[128 * 32], Asl[128 * 32];
  __shared__ __align__(16) u16 Bsh[128 * 32], Bsl[128 * 32];
  int tid = threadIdx.x, w = tid >> 6, l = tid & 63;
  int quad = l >> 4, l15 = l & 15;
  int m0 = blockIdx.x * 128, n0 = blockIdx.y * 128;
  int koff = (l & 3) * 8;
  const u16 *aph[2], *apl[2], *bph[2], *bpl[2];
  #pragma unroll
  for (int c = 0; c < 2; ++c) {
    int chunk = c * 4 + w;
    int row = m0 + chunk * 16 + (l >> 2);
    aph[c] = Ah + (size_t)row * K + koff;
    apl[c] = Al + (size_t)row * K + koff;
    int nrow = n0 + chunk * 16 + (l >> 2);
    bph[c] = Bh + (size_t)nrow * K + koff;
    bpl[c] = Bl + (size_t)nrow * K + koff;
  }
  f32x4 acc[4][4] = {};
  int wm = (w & 1) * 64, wn = (w >> 1) * 64;
  for (int k0 = 0; k0 < K; k0 += 32) {
    __syncthreads();
    #pragma unroll
    for (int c = 0; c < 2; ++c) {
      gload16(aph[c] + k0, &Ash[(c * 4 + w) * 512]);
      gload16(apl[c] + k0, &Asl[(c * 4 + w) * 512]);
      gload16(bph[c] + k0, &Bsh[(c * 4 + w) * 512]);
      gload16(bpl[c] + k0, &Bsl[(c * 4 + w) * 512]);
    }
    __syncthreads();
    bf16x8 ah[4], al_[4], bh[4], bl_[4];
    #pragma unroll
    for (int i = 0; i < 4; ++i) {
      ah[i] = *(const bf16x8*)&Ash[(wm + i * 16 + l15) * 32 + quad * 8];
      al_[i] = *(const bf16x8*)&Asl[(wm + i * 16 + l15) * 32 + quad * 8];
    }
    #pragma unroll
    for (int j = 0; j < 4; ++j) {
      bh[j] = *(const bf16x8*)&Bsh[(wn + j * 16 + l15) * 32 + quad * 8];
      bl_[j] = *(const bf16x8*)&Bsl[(wn + j * 16 + l15) * 32 + quad * 8];
    }
    #pragma unroll
    for (int i = 0; i < 4; ++i)
      #pragma unroll
      for (int j = 0; j < 4; ++j) {
        acc[i][j] = __builtin_amdgcn_mfma_f32_16x16x32_bf16(ah[i], bh[j], acc[i][j], 0, 0, 0);
        acc[i][j] = __builtin_amdgcn_mfma_f32_16x16x32_bf16(ah[i], bl_[j], acc[i][j], 0, 0, 0);
        acc[i][j] = __builtin_amdgcn_mfma_f32_16x16x32_bf16(al_[i], bh[j], acc[i][j], 0, 0, 0);
      }
  }
  #pragma unroll
  for (int i = 0; i < 4; ++i) {
    #pragma unroll
    for (int j = 0; j < 4; ++j) {
      int gn = n0 + wn + j * 16 + l15;
      float bv = bias[gn];
      #pragma unroll
      for (int r = 0; r < 4; ++r) {
        int gm = m0 + wm + i * 16 + quad * 4 + r;
        size_t idx = (size_t)gm * N + gn;
        float v = acc[i][j][r] + bv;
        if (OUTMODE == 0) {
          u16 h = f2b(v);
          Ch[idx] = h;
          Cl[idx] = f2b(v - b2f(h));
        } else {
          Cf[idx] = v + res[idx];
        }
      }
    }
  }
}

// ---------------- V transpose with pi-permutation ----------------
// vt[(b*G+g)*HD + d][s0 + pi(s)] = qkv_V[b, s0+s, g, d],  pi(u)=(u&15)*4+(u>>4)
// Sum over s is permutation-invariant, so attention P (stored at pi(s)) and
// V rows (stored at pi(s)) stay consistent while making both LDS-cheap.
__global__ __launch_bounds__(256) void k_vt(const u16* __restrict__ qkv,
                                            u16* __restrict__ vt) {
  __shared__ u16 tile[64][72];
  int bg = blockIdx.y;  // b*G + g
  int b = bg >> 2, g = bg & 3;
  int s0 = blockIdx.x * 64;
  int tid = threadIdx.x;
  int r = tid >> 2, cb = (tid & 3) * 16;
  const u16* src = qkv + (size_t)(b * S_ + s0 + r) * 1536 + 1280 + g * HD_ + cb;
  int pr = ((r & 15) * 4) | (r >> 4);
  #pragma unroll
  for (int c = 0; c < 4; ++c) {
    ushort4 v = *(const ushort4*)&src[c * 4];
    tile[cb + c * 4 + 0][pr] = v.x;
    tile[cb + c * 4 + 1][pr] = v.y;
    tile[cb + c * 4 + 2][pr] = v.z;
    tile[cb + c * 4 + 3][pr] = v.w;
  }
  __syncthreads();
  int d = tid >> 2, scol = (tid & 3) * 16;
  u16* dst = vt + ((size_t)bg * HD_ + d) * S_ + s0 + scol;
  #pragma unroll
  for (int c = 0; c < 4; ++c)
    *(ushort4*)&dst[c * 4] = *(const ushort4*)&tile[d][scol + c * 4];
}

// ---------------- MFMA flash attention with session-delta decay ----------------
// V pre-transposed+permuted (k_vt); P stored permuted (contiguous b64 writes).
#define AP 72  // padded u16 row stride for LDS tiles
__global__ __launch_bounds__(256) void k_attn_mfma(const u16* __restrict__ qkv_h,
                                                   const u16* __restrict__ qkv_l,
                                                   const u16* __restrict__ vth_g,
                                                   const u16* __restrict__ vtl_g,
                                                   const float* __restrict__ sd,
                                                   const float* __restrict__ td,
                                                   u16* __restrict__ o_h,
                                                   u16* __restrict__ o_l) {
  __shared__ __align__(16) u16 Qh[64 * AP], Ql[64 * AP];
  __shared__ __align__(16) u16 Kh[64 * AP], Kl[64 * AP];
  __shared__ __align__(16) u16 Vth[64 * AP], Vtl[64 * AP];
  __shared__ __align__(16) u16 Ph[4][16 * AP], Pl[4][16 * AP];
  int tid = threadIdx.x, w = tid >> 6, l = tid & 63;
  int quad = l >> 4, l15 = l & 15;
  int q0 = blockIdx.x * 64, h = blockIdx.y, b = blockIdx.z;
  int g = h >> 2;
  int bg = b * G_ + g;
  int r = tid >> 2, cb = (tid & 3) * 16;

  {
    const u16* gq_h = qkv_h + (size_t)(b * S_ + q0 + r) * 1536 + h * HD_ + cb;
    const u16* gq_l = qkv_l + (size_t)(b * S_ + q0 + r) * 1536 + h * HD_ + cb;
    #pragma unroll
    for (int c = 0; c < 4; ++c) {
      *(ushort4*)&Qh[r * AP + cb + c * 4] = *(const ushort4*)&gq_h[c * 4];
      *(ushort4*)&Ql[r * AP + cb + c * 4] = *(const ushort4*)&gq_l[c * 4];
    }
  }
  __syncthreads();
  bf16x8 aqh[2], aql[2];
  #pragma unroll
  for (int kk = 0; kk < 2; ++kk) {
    aqh[kk] = *(const bf16x8*)&Qh[(w * 16 + l15) * AP + kk * 32 + quad * 8];
    aql[kk] = *(const bf16x8*)&Ql[(w * 16 + l15) * AP + kk * 32 + quad * 8];
  }
  float sp = log1pf(__expf(td[h]));
  float dq[4];
  #pragma unroll
  for (int i = 0; i < 4; ++i) dq[i] = sd[b * S_ + q0 + w * 16 + quad * 4 + i];

  float mr[4], lr[4];
  f32x4 oa[4] = {};
  #pragma unroll
  for (int i = 0; i < 4; ++i) { mr[i] = -3.0e38f; lr[i] = 0.f; }

  for (int s0 = 0; s0 < S_; s0 += 64) {
    const u16* gk_h = qkv_h + (size_t)(b * S_ + s0 + r) * 1536 + 1024 + g * HD_ + cb;
    const u16* gk_l = qkv_l + (size_t)(b * S_ + s0 + r) * 1536 + 1024 + g * HD_ + cb;
    const u16* gvt_h = vth_g + ((size_t)bg * HD_ + r) * S_ + s0 + cb;
    const u16* gvt_l = vtl_g + ((size_t)bg * HD_ + r) * S_ + s0 + cb;
    ushort4 kh4[4], kl4[4], vth4[4], vtl4[4];
    #pragma unroll
    for (int c = 0; c < 4; ++c) {
      kh4[c] = *(const ushort4*)&gk_h[c * 4];
      kl4[c] = *(const ushort4*)&gk_l[c * 4];
      vth4[c] = *(const ushort4*)&gvt_h[c * 4];
      vtl4[c] = *(const ushort4*)&gvt_l[c * 4];
    }
    float dsv[4];
    #pragma unroll
    for (int j = 0; j < 4; ++j) dsv[j] = sd[b * S_ + s0 + j * 16 + l15];
    __syncthreads();
    #pragma unroll
    for (int c = 0; c < 4; ++c) {
      *(ushort4*)&Kh[r * AP + cb + c * 4] = kh4[c];
      *(ushort4*)&Kl[r * AP + cb + c * 4] = kl4[c];
      *(ushort4*)&Vth[r * AP + cb + c * 4] = vth4[c];
      *(ushort4*)&Vtl[r * AP + cb + c * 4] = vtl4[c];
    }
    __syncthreads();

    f32x4 sc[4] = {};
    __builtin_amdgcn_s_setprio(1);
    #pragma unroll
    for (int j = 0; j < 4; ++j) {
      #pragma unroll
      for (int kk = 0; kk < 2; ++kk) {
        bf16x8 bkh = *(const bf16x8*)&Kh[(j * 16 + l15) * AP + kk * 32 + quad * 8];
        bf16x8 bkl = *(const bf16x8*)&Kl[(j * 16 + l15) * AP + kk * 32 + quad * 8];
        sc[j] = __builtin_amdgcn_mfma_f32_16x16x32_bf16(aqh[kk], bkh, sc[j], 0, 0, 0);
        sc[j] = __builtin_amdgcn_mfma_f32_16x16x32_bf16(aqh[kk], bkl, sc[j], 0, 0, 0);
        sc[j] = __builtin_amdgcn_mfma_f32_16x16x32_bf16(aql[kk], bkh, sc[j], 0, 0, 0);
      }
    }
    __builtin_amdgcn_s_setprio(0);
    float s_[4][4];
    #pragma unroll
    for (int j = 0; j < 4; ++j)
      #pragma unroll
      for (int i = 0; i < 4; ++i)
        s_[j][i] = sc[j][i] * 0.125f - sp * fabsf(dq[i] - dsv[j]);
    float mx[4];
    #pragma unroll
    for (int i = 0; i < 4; ++i)
      mx[i] = fmaxf(fmaxf(s_[0][i], s_[1][i]), fmaxf(s_[2][i], s_[3][i]));
    #pragma unroll
    for (int d = 1; d < 16; d <<= 1)
      #pragma unroll
      for (int i = 0; i < 4; ++i) mx[i] = fmaxf(mx[i], __shfl_xor(mx[i], d));
    float al[4], rsum[4], p[4][4];
    #pragma unroll
    for (int i = 0; i < 4; ++i) {
      float mn = fmaxf(mr[i], mx[i]);
      al[i] = __expf(mr[i] - mn);
      mr[i] = mn;
      rsum[i] = 0.f;
      #pragma unroll
      for (int j = 0; j < 4; ++j) { p[j][i] = __expf(s_[j][i] - mn); rsum[i] += p[j][i]; }
    }
    #pragma unroll
    for (int d = 1; d < 16; d <<= 1)
      #pragma unroll
      for (int i = 0; i < 4; ++i) rsum[i] += __shfl_xor(rsum[i], d);
    #pragma unroll
    for (int i = 0; i < 4; ++i) {
      lr[i] = lr[i] * al[i] + rsum[i];
      #pragma unroll
      for (int j = 0; j < 4; ++j) oa[j][i] *= al[i];
    }
    // P stored at permuted col s' = l15*4 + j (pi of s = j*16+l15): b64 writes
    #pragma unroll
    for (int i = 0; i < 4; ++i) {
      u16 h0 = f2b(p[0][i]), h1 = f2b(p[1][i]), h2 = f2b(p[2][i]), h3 = f2b(p[3][i]);
      uint2 ph2;
      ph2.x = (unsigned)h0 | ((unsigned)h1 << 16);
      ph2.y = (unsigned)h2 | ((unsigned)h3 << 16);
      *(uint2*)&Ph[w][(quad * 4 + i) * AP + l15 * 4] = ph2;
      u16 e0 = f2b(p[0][i] - b2f(h0)), e1 = f2b(p[1][i] - b2f(h1));
      u16 e2 = f2b(p[2][i] - b2f(h2)), e3 = f2b(p[3][i] - b2f(h3));
      uint2 pl2;
      pl2.x = (unsigned)e0 | ((unsigned)e1 << 16);
      pl2.y = (unsigned)e2 | ((unsigned)e3 << 16);
      *(uint2*)&Pl[w][(quad * 4 + i) * AP + l15 * 4] = pl2;
    }
    bf16x8 aph[2], apl[2];
    #pragma unroll
    for (int kk = 0; kk < 2; ++kk) {
      aph[kk] = *(const bf16x8*)&Ph[w][l15 * AP + kk * 32 + quad * 8];
      apl[kk] = *(const bf16x8*)&Pl[w][l15 * AP + kk * 32 + quad * 8];
    }
    __builtin_amdgcn_s_setprio(1);
    #pragma unroll
    for (int j = 0; j < 4; ++j) {
      #pragma unroll
      for (int kk = 0; kk < 2; ++kk) {
        bf16x8 bvh = *(const bf16x8*)&Vth[(j * 16 + l15) * AP + kk * 32 + quad * 8];
        bf16x8 bvl = *(const bf16x8*)&Vtl[(j * 16 + l15) * AP + kk * 32 + quad * 8];
        oa[j] = __builtin_amdgcn_mfma_f32_16x16x32_bf16(aph[kk], bvh, oa[j], 0, 0, 0);
        oa[j] = __builtin_amdgcn_mfma_f32_16x16x32_bf16(aph[kk], bvl, oa[j], 0, 0, 0);
        oa[j] = __builtin_amdgcn_mfma_f32_16x16x32_bf16(apl[kk], bvh, oa[j], 0, 0, 0);
      }
    }
    __builtin_amdgcn_s_setprio(0);
  }
  #pragma unroll
  for (int i = 0; i < 4; ++i) {
    float inv = 1.f / lr[i];
    int q = b * S_ + q0 + w * 16 + quad * 4 + i;
    #pragma unroll
    for (int j = 0; j < 4; ++j) {
      float ov = oa[j][i] * inv;
      size_t idx = (size_t)q * (H_ * HD_) + h * HD_ + j * 16 + l15;
      u16 hv = f2b(ov);
      o_h[idx] = hv;
      o_l[idx] = f2b(ov - b2f(hv));
    }
  }
}

// ---------------- router ----------------
__global__ __launch_bounds__(256) void k_router(const float* __restrict__ xn2,
                                                const float* __restrict__ rw,
                                                const float* __restrict__ rb,
                                                int* __restrict__ eidx, int* __restrict__ epos,
                                                float* __restrict__ ew, int* __restrict__ cnt,
                                                int* __restrict__ list) {
  int t = blockIdx.x * 4 + (threadIdx.x >> 6);
  int l = threadIdx.x & 63;
  const float* row = xn2 + (size_t)t * D_;
  float acc[8];
  #pragma unroll
  for (int e = 0; e < 8; ++e) acc[e] = 0.f;
  for (int i = 0; i < 16; ++i) {
    int d = l + i * 64;
    float xv = row[d];
    float4 w0 = *(const float4*)&rw[d * 8 + 0];
    float4 w1 = *(const float4*)&rw[d * 8 + 4];
    acc[0] = fmaf(xv, w0.x, acc[0]); acc[1] = fmaf(xv, w0.y, acc[1]);
    acc[2] = fmaf(xv, w0.z, acc[2]); acc[3] = fmaf(xv, w0.w, acc[3]);
    acc[4] = fmaf(xv, w1.x, acc[4]); acc[5] = fmaf(xv, w1.y, acc[5]);
    acc[6] = fmaf(xv, w1.z, acc[6]); acc[7] = fmaf(xv, w1.w, acc[7]);
  }
  #pragma unroll
  for (int off = 32; off > 0; off >>= 1)
    #pragma unroll
    for (int e = 0; e < 8; ++e) acc[e] += __shfl_xor(acc[e], off);
  if (l == 0) {
    float lg[8];
    #pragma unroll
    for (int e = 0; e < 8; ++e) lg[e] = acc[e] + rb[e];
    int i1 = 0;
    #pragma unroll
    for (int e = 1; e < 8; ++e) if (lg[e] > lg[i1]) i1 = e;
    int i2 = (i1 == 0) ? 1 : 0;
    #pragma unroll
    for (int e = 0; e < 8; ++e) if (e != i1 && lg[e] > lg[i2]) i2 = e;
    float wa = 1.f / (1.f + __expf(lg[i2] - lg[i1]));
    float wb = 1.f - wa;
    int pa = atomicAdd(&cnt[i1], 1);
    int pb = atomicAdd(&cnt[i2], 1);
    list[i1 * T_ + pa] = t;
    list[i2 * T_ + pb] = t;
    eidx[2 * t] = i1; eidx[2 * t + 1] = i2;
    epos[2 * t] = pa; epos[2 * t + 1] = pb;
    ew[2 * t] = wa; ew[2 * t + 1] = wb;
  }
}

// offs[0..7] = slot prefix; offs[8..15] = 128-row tile prefix; offs[16] = total tiles
__global__ void k_offsets(const int* __restrict__ cnt, int* __restrict__ offs) {
  if (threadIdx.x == 0 && blockIdx.x == 0) {
    int tot = 0, ttot = 0;
    for (int e = 0; e < E_; ++e) {
      offs[e] = tot; tot += cnt[e];
      offs[8 + e] = ttot; ttot += (cnt[e] + 127) >> 7;
    }
    offs[16] = ttot;
  }
}

// ---------------- gather A rows densely per expert slot ----------------
__global__ __launch_bounds__(128) void k_gather(const u16* __restrict__ src,
                                                const int* __restrict__ offs,
                                                const int* __restrict__ list,
                                                u16* __restrict__ dst) {
  int s = blockIdx.x;  // slot 0 .. 2*T_-1
  int e = 0;
  #pragma unroll
  for (int i = 1; i < E_; ++i) e = (s >= offs[i]) ? i : e;
  int tok = list[e * T_ + (s - offs[e])];
  int l = threadIdx.x;  // 128 threads x 8 u16 = 1024
  ushort4 a = *(const ushort4*)&src[(size_t)tok * D_ + l * 8];
  ushort4 b = *(const ushort4*)&src[(size_t)tok * D_ + l * 8 + 4];
  *(ushort4*)&dst[(size_t)s * D_ + l * 8] = a;
  *(ushort4*)&dst[(size_t)s * D_ + l * 8 + 4] = b;
}

// ---------------- bf16 MFMA GEMM for MoE ----------------
// Dense 1-D work grid; XCD-bijective swizzle; 3-buffer LDS, depth-2 prefetch,
// counted vmcnt, raw s_barrier, setprio.
template <int MODE, int LOGNY>
__global__ __launch_bounds__(256) void k_moe_gemm(const u16* __restrict__ Ab,
                                                  const u16* __restrict__ Wt,
                                                  const float* __restrict__ bias,
                                                  u16* __restrict__ outU,
                                                  const int* __restrict__ cnt,
                                                  const int* __restrict__ meta,
                                                  int N, int K) {
  int q = gridDim.x >> 3;
  int wid = (blockIdx.x & 7) * q + (blockIdx.x >> 3);
  int tx = wid >> LOGNY;
  int ny = wid & ((1 << LOGNY) - 1);
  if (tx >= meta[16]) return;
  int e = 0;
  #pragma unroll
  for (int i = 1; i < E_; ++i) e = (tx >= meta[8 + i]) ? i : e;
  int myM = cnt[e];
  int m0 = (tx - meta[8 + e]) * 128;
  int n0 = ny * 128;
  __shared__ __align__(16) u16 As[3][128 * 32];
  __shared__ __align__(16) u16 Bs[3][128 * 32];
  int tid = threadIdx.x, w = tid >> 6, l = tid & 63;
  int quad = l >> 4, l15 = l & 15;
  int koff = (l & 3) * 8;
  const u16* ap[2];
  const u16* bp[2];
  #pragma unroll
  for (int c = 0; c < 2; ++c) {
    int chunk = c * 4 + w;
    int r = m0 + chunk * 16 + (l >> 2);
    int rr = (r < myM) ? r : (myM - 1);
    ap[c] = Ab + (size_t)(meta[e] + rr) * K + koff;
    int nrow = n0 + chunk * 16 + (l >> 2);
    bp[c] = Wt + (size_t)e * N * K + (size_t)nrow * K + koff;
  }
  f32x4 acc[4][4] = {};
  int wm = (w & 1) * 64, wn = (w >> 1) * 64;
  int nsteps = K >> 5;
  #pragma unroll
  for (int c = 0; c < 2; ++c) {
    gload16(ap[c], &As[0][(c * 4 + w) * 512]);
    gload16(bp[c], &Bs[0][(c * 4 + w) * 512]);
  }
  #pragma unroll
  for (int c = 0; c < 2; ++c) {
    gload16(ap[c] + 32, &As[1][(c * 4 + w) * 512]);
    gload16(bp[c] + 32, &Bs[1][(c * 4 + w) * 512]);
  }
  int cur = 0, stg = 2;
  for (int it = 0; it < nsteps - 1; ++it) {
    asm volatile("s_waitcnt vmcnt(4)" ::: "memory");
    asm volatile("s_barrier" ::: "memory");
    if (it < nsteps - 2) {
      int k0 = (it + 2) << 5;
      #pragma unroll
      for (int c = 0; c < 2; ++c) {
        gload16(ap[c] + k0, &As[stg][(c * 4 + w) * 512]);
        gload16(bp[c] + k0, &Bs[stg][(c * 4 + w) * 512]);
      }
    }
    bf16x8 af[4], bfv[4];
    #pragma unroll
    for (int i = 0; i < 4; ++i)
      af[i] = *(const bf16x8*)&As[cur][(wm + i * 16 + l15) * 32 + quad * 8];
    #pragma unroll
    for (int j = 0; j < 4; ++j)
      bfv[j] = *(const bf16x8*)&Bs[cur][(wn + j * 16 + l15) * 32 + quad * 8];
    __builtin_amdgcn_s_setprio(1);
    #pragma unroll
    for (int i = 0; i < 4; ++i)
      #pragma unroll
      for (int j = 0; j < 4; ++j)
        acc[i][j] = __builtin_amdgcn_mfma_f32_16x16x32_bf16(af[i], bfv[j], acc[i][j], 0, 0, 0);
    __builtin_amdgcn_s_setprio(0);
    cur = (cur == 2) ? 0 : cur + 1;
    stg = (stg == 2) ? 0 : stg + 1;
  }
  asm volatile("s_waitcnt vmcnt(0)" ::: "memory");
  asm volatile("s_barrier" ::: "memory");
  {
    bf16x8 af[4], bfv[4];
    #pragma unroll
    for (int i = 0; i < 4; ++i)
      af[i] = *(const bf16x8*)&As[cur][(wm + i * 16 + l15) * 32 + quad * 8];
    #pragma unroll
    for (int j = 0; j < 4; ++j)
      bfv[j] = *(const bf16x8*)&Bs[cur][(wn + j * 16 + l15) * 32 + quad * 8];
    __builtin_amdgcn_s_setprio(1);
    #pragma unroll
    for (int i = 0; i < 4; ++i)
      #pragma unroll
      for (int j = 0; j < 4; ++j)
        acc[i][j] = __builtin_amdgcn_mfma_f32_16x16x32_bf16(af[i], bfv[j], acc[i][j], 0, 0, 0);
    __builtin_amdgcn_s_setprio(0);
  }
  const float* bptr = bias + (size_t)e * N;
  #pragma unroll
  for (int i = 0; i < 4; ++i) {
    #pragma unroll
    for (int j = 0; j < 4; ++j) {
      int gn = n0 + wn + j * 16 + l15;
      float bv = bptr[gn];
      #pragma unroll
      for (int r = 0; r < 4; ++r) {
        int gm = m0 + wm + i * 16 + quad * 4 + r;
        if (gm < myM) {
          float vv = acc[i][j][r] + bv;
          if (MODE == 0) vv = gelu_t(vv);
          outU[(size_t)(meta[e] + gm) * N + gn] = f2b(vv);
        }
      }
    }
  }
}

// ---------------- final combine ----------------
__global__ __launch_bounds__(256) void k_combine(const float* __restrict__ x1,
                                                 const u16* __restrict__ y,
                                                 const int* __restrict__ eidx,
                                                 const int* __restrict__ epos,
                                                 const float* __restrict__ ew,
                                                 const int* __restrict__ offs,
                                                 float* __restrict__ out) {
  int t = blockIdx.x, tid = threadIdx.x;
  int e0 = eidx[2 * t], e1 = eidx[2 * t + 1];
  int s0 = offs[e0] + epos[2 * t];
  int s1 = offs[e1] + epos[2 * t + 1];
  float w0 = ew[2 * t], w1 = ew[2 * t + 1];
  int d = tid * 4;
  float4 a = *(const float4*)&x1[(size_t)t * D_ + d];
  ushort4 y0 = *(const ushort4*)&y[(size_t)s0 * D_ + d];
  ushort4 y1 = *(const ushort4*)&y[(size_t)s1 * D_ + d];
  float4 r;
  r.x = a.x + w0 * b2f(y0.x) + w1 * b2f(y1.x);
  r.y = a.y + w0 * b2f(y0.y) + w1 * b2f(y1.y);
  r.z = a.z + w0 * b2f(y0.z) + w1 * b2f(y1.z);
  r.w = a.w + w0 * b2f(y0.w) + w1 * b2f(y1.w);
  *(float4*)&out[(size_t)t * D_ + d] = r;
}

// ---------------- launch ----------------
extern "C" void kernel_launch(void* const* d_in, const int* in_sizes, int n_in,
                              void* d_out, int out_size, void* d_ws, size_t ws_size,
                              hipStream_t stream) {
  (void)in_sizes; (void)n_in; (void)out_size; (void)ws_size;
  const float* x    = (const float*)d_in[0];
  const float* sd   = (const float*)d_in[1];
  const float* ln1s = (const float*)d_in[2];
  const float* ln1b = (const float*)d_in[3];
  const float* wq   = (const float*)d_in[4];
  const float* bq   = (const float*)d_in[5];
  const float* wk   = (const float*)d_in[6];
  const float* bk   = (const float*)d_in[7];
  const float* wv   = (const float*)d_in[8];
  const float* bv   = (const float*)d_in[9];
  const float* wo   = (const float*)d_in[10];
  const float* bo   = (const float*)d_in[11];
  const float* td   = (const float*)d_in[12];
  const float* ln2s = (const float*)d_in[13];
  const float* ln2b = (const float*)d_in[14];
  const float* rw   = (const float*)d_in[15];
  const float* rb   = (const float*)d_in[16];
  const float* w1   = (const float*)d_in[17];
  const float* b1   = (const float*)d_in[18];
  const float* w2   = (const float*)d_in[19];
  const float* b2   = (const float*)d_in[20];
  float* out = (float*)d_out;

  const size_t MBy = 1024ull * 1024ull;
  char* ws = (char*)d_ws;
  u16*   w1t   = (u16*)(ws + 0);          // 64MB   [prep -> moe1]
  u16*   w2t   = (u16*)(ws + 64 * MBy);   // 64MB   [prep -> moe2]
  u16*   hb    = (u16*)(ws + 128 * MBy);  // 64MB   [moe1 -> moe2]
  float* xn2   = (float*)(ws + 128 * MBy);// 16MB   aliases hb (dead before moe1)
  u16*   vth   = (u16*)(ws + 128 * MBy);  // 2MB    aliases hb/xn2 [k_vt -> attn]
  u16*   vtl   = (u16*)(ws + 131 * MBy);  // 2MB    (dead before ln2 writes xn2)
  u16*   wqkvTh= (u16*)(ws + 192 * MBy);  // 3MB
  u16*   wqkvTl= (u16*)(ws + 195 * MBy);  // 3MB
  u16*   woTh  = (u16*)(ws + 198 * MBy);  // 2MB
  u16*   woTl  = (u16*)(ws + 200 * MBy);  // 2MB
  float* bqkv  = (float*)(ws + 202 * MBy);// 6KB
  int*   eidx  = (int*)(ws + 202 * MBy + 65536);
  int*   epos  = eidx + 2 * T_;
  float* ew    = (float*)(epos + 2 * T_);
  int*   list  = (int*)(ew + 2 * T_);
  int*   cnt   = list + E_ * T_;
  int*   offs  = cnt + E_;               // 17 ints: slots[8] | tiles[8] | ttot
  u16*   xn_h  = (u16*)(ws + 203 * MBy);  // 8MB    [ln1 -> qkv gemm]
  u16*   xn_l  = (u16*)(ws + 211 * MBy);  // 8MB
  u16*   xn2b  = (u16*)(ws + 203 * MBy);  // 8MB    aliases xn_h (dead)
  u16*   qkv_h = (u16*)(ws + 219 * MBy);  // 13MB   [qkv -> attn]
  u16*   qkv_l = (u16*)(ws + 232 * MBy);  // 13MB
  u16*   yb    = (u16*)(ws + 219 * MBy);  // 16MB   aliases qkv (dead after attn)
  u16*   o_h   = (u16*)(ws + 245 * MBy);  // 8MB    [attn -> outproj]
  u16*   o_l   = (u16*)(ws + 253 * MBy);  // 8MB
  u16*   aprime= (u16*)(ws + 245 * MBy);  // 16MB   aliases o_h/o_l (dead after outproj)
  float* x1    = (float*)(ws + 261 * MBy);// 16MB   [outproj -> combine]

  k_zero<<<1, 64, 0, stream>>>(cnt);
  k_transpose<<<dim3(F_ / 32, D_ / 32, E_), dim3(32, 8), 0, stream>>>(w1, w1t, D_, F_);
  k_transpose<<<dim3(D_ / 32, F_ / 32, E_), dim3(32, 8), 0, stream>>>(w2, w2t, F_, D_);
  k_split_transpose<<<dim3(1024 / 32, 1024 / 32), dim3(32, 8), 0, stream>>>(wq, wqkvTh, wqkvTl, 1024, 1024);
  k_split_transpose<<<dim3(256 / 32, 1024 / 32), dim3(32, 8), 0, stream>>>(wk, wqkvTh + 1024 * 1024, wqkvTl + 1024 * 1024, 1024, 256);
  k_split_transpose<<<dim3(256 / 32, 1024 / 32), dim3(32, 8), 0, stream>>>(wv, wqkvTh + 1280 * 1024, wqkvTl + 1280 * 1024, 1024, 256);
  k_split_transpose<<<dim3(1024 / 32, 1024 / 32), dim3(32, 8), 0, stream>>>(wo, woTh, woTl, 1024, 1024);
  k_prep_bias<<<6, 256, 0, stream>>>(bq, bk, bv, bqkv);

  k_ln<<<T_, 256, 0, stream>>>(x, ln1s, ln1b, nullptr, nullptr, xn_h, xn_l);

  k_gemm_split<0><<<dim3(T_ / 128, 1536 / 128), 256, 0, stream>>>(
      xn_h, xn_l, wqkvTh, wqkvTl, bqkv, nullptr, qkv_h, qkv_l, nullptr, T_, 1536, 1024);

  k_vt<<<dim3(S_ / 64, B_ * G_), 256, 0, stream>>>(qkv_h, vth);
  k_vt<<<dim3(S_ / 64, B_ * G_), 256, 0, stream>>>(qkv_l, vtl);

  k_attn_mfma<<<dim3(S_ / 64, H_, B_), 256, 0, stream>>>(qkv_h, qkv_l, vth, vtl, sd, td, o_h, o_l);

  k_gemm_split<1><<<dim3(T_ / 128, 1024 / 128), 256, 0, stream>>>(
      o_h, o_l, woTh, woTl, bo, x, nullptr, nullptr, x1, T_, 1024, 1024);

  k_ln<<<T_, 256, 0, stream>>>(x1, ln2s, ln2b, xn2, xn2b, nullptr, nullptr);

  k_router<<<T_ / 4, 256, 0, stream>>>(xn2, rw, rb, eidx, epos, ew, cnt, list);
  k_offsets<<<1, 64, 0, stream>>>(cnt, offs);
  k_gather<<<2 * T_, 128, 0, stream>>>(xn2b, offs, list, aprime);

  k_moe_gemm<0, 5><<<dim3(72 * 32), 256, 0, stream>>>(aprime, w1t, b1, hb, cnt, offs, F_, D_);
  k_moe_gemm<1, 3><<<dim3(72 * 8), 256, 0, stream>>>(hb, w2t, b2, yb, cnt, offs, D_, F_);

  k_combine<<<T_, 256, 0, stream>>>(x1, yb, eidx, epos, ew, offs, out);
}